// Round 5
// baseline (598.713 us; speedup 1.0000x reference)
//
#include <hip/hip_runtime.h>

typedef __attribute__((ext_vector_type(4))) float f32x4;
typedef __attribute__((ext_vector_type(8))) short bf16x8;
typedef __attribute__((ext_vector_type(8))) unsigned short u16x8;
typedef __attribute__((ext_vector_type(4))) unsigned short u16x4;

#define DEV static __device__ __forceinline__

// sizes fixed by the problem
#define BQ 4
#define SQ 2048
#define DM 1024
#define HH 16
#define DK 64
#define MM (BQ * SQ)   // 8192

DEV unsigned short f2bf(float f) {
    unsigned int u = __builtin_bit_cast(unsigned int, f);
    u += 0x7fffu + ((u >> 16) & 1u);               // RNE
    return (unsigned short)(u >> 16);
}

DEV void gll16(const void* g, void* l) {           // async global->LDS, 16B/lane
    __builtin_amdgcn_global_load_lds(
        (const __attribute__((address_space(1))) unsigned int*)g,
        (__attribute__((address_space(3))) unsigned int*)l, 16, 0, 0);
}

// swizzles: XOR row bits into byte bits 4.. to break same-bank column reads
#define SWZ64(b)  ((b) ^ ((((b) >> 6) & 3) << 4))   // row stride 64B
#define SWZ128(b) ((b) ^ ((((b) >> 7) & 7) << 4))   // row stride 128B
#define SWZ256(b) ((b) ^ ((((b) >> 8) & 7) << 4))   // row stride 256B

// ---------------------------------------------------------------------------
// C = A @ W^T + bias.  A:[8192x1024] , W:[1024x1024] fp32 row-major.
// MODE 0: A fp32, C bf16 laid out [B,H,S,Dk]        (Q, K)
// MODE 1: A fp32, C bf16 laid out [B,H,Dk,S]        (V transposed)
// MODE 2: A bf16, C fp32 laid out [8192,1024]       (final projection)
// 128x128 tile, BK=32, 4 waves each computing 64x64 via 16x16x32 bf16 MFMA.
// ---------------------------------------------------------------------------
template <int MODE>
__global__ __launch_bounds__(256, 2)
void gemm_bt(const void* __restrict__ Av, const float* __restrict__ Wf,
             const float* __restrict__ bias, void* __restrict__ Cv)
{
    __shared__ unsigned short As[128 * 32];
    __shared__ unsigned short Bs[128 * 32];
    char* Asb = (char*)As;
    char* Bsb = (char*)Bs;

    const int tid = threadIdx.x, lane = tid & 63, wid = tid >> 6;
    const int l15 = lane & 15, lg = lane >> 4;
    const int wr = wid >> 1, wc = wid & 1;
    const int m0 = blockIdx.x * 128, n0 = blockIdx.y * 128;
    const int sr = tid >> 1, sc = (tid & 1) * 16;     // staging row / col-elem

    f32x4 acc[4][4];
#pragma unroll
    for (int i = 0; i < 4; ++i)
#pragma unroll
        for (int j = 0; j < 4; ++j) acc[i][j] = (f32x4){0.f, 0.f, 0.f, 0.f};

    for (int kt = 0; kt < 32; ++kt) {
        const int k0 = kt * 32;
        u16x8 av0, av1, bv0, bv1;
        if (MODE == 2) {
            const unsigned short* Ap =
                (const unsigned short*)Av + (size_t)(m0 + sr) * DM + k0 + sc;
            av0 = *(const u16x8*)Ap;
            av1 = *(const u16x8*)(Ap + 8);
        } else {
            const float* Ap = (const float*)Av + (size_t)(m0 + sr) * DM + k0 + sc;
            f32x4 a0 = *(const f32x4*)Ap,       a1 = *(const f32x4*)(Ap + 4);
            f32x4 a2 = *(const f32x4*)(Ap + 8), a3 = *(const f32x4*)(Ap + 12);
#pragma unroll
            for (int i = 0; i < 4; ++i) {
                av0[i] = f2bf(a0[i]); av0[4 + i] = f2bf(a1[i]);
                av1[i] = f2bf(a2[i]); av1[4 + i] = f2bf(a3[i]);
            }
        }
        {
            const float* Bp = Wf + (size_t)(n0 + sr) * DM + k0 + sc;
            f32x4 b0 = *(const f32x4*)Bp,       b1 = *(const f32x4*)(Bp + 4);
            f32x4 b2 = *(const f32x4*)(Bp + 8), b3 = *(const f32x4*)(Bp + 12);
#pragma unroll
            for (int i = 0; i < 4; ++i) {
                bv0[i] = f2bf(b0[i]); bv0[4 + i] = f2bf(b1[i]);
                bv1[i] = f2bf(b2[i]); bv1[4 + i] = f2bf(b3[i]);
            }
        }
        __syncthreads();                       // prev-iter reads done
        const int lb = sr * 64 + sc * 2;
        *(u16x8*)(Asb + SWZ64(lb))      = av0;
        *(u16x8*)(Asb + SWZ64(lb + 16)) = av1;
        *(u16x8*)(Bsb + SWZ64(lb))      = bv0;
        *(u16x8*)(Bsb + SWZ64(lb + 16)) = bv1;
        __syncthreads();                       // staging visible

        bf16x8 af[4], bfr[4];
#pragma unroll
        for (int mi = 0; mi < 4; ++mi) {
            int o = (wr * 64 + mi * 16 + l15) * 64 + lg * 16;
            af[mi] = *(const bf16x8*)(Asb + SWZ64(o));
        }
#pragma unroll
        for (int ni = 0; ni < 4; ++ni) {
            int o = (wc * 64 + ni * 16 + l15) * 64 + lg * 16;
            bfr[ni] = *(const bf16x8*)(Bsb + SWZ64(o));
        }
#pragma unroll
        for (int mi = 0; mi < 4; ++mi)
#pragma unroll
            for (int ni = 0; ni < 4; ++ni)
                acc[mi][ni] = __builtin_amdgcn_mfma_f32_16x16x32_bf16(
                    af[mi], bfr[ni], acc[mi][ni], 0, 0, 0);
    }

    // epilogue: C row = m0+wr*64+mi*16+lg*4+j, col = n0+wc*64+ni*16+l15
#pragma unroll
    for (int ni = 0; ni < 4; ++ni) {
        const int n = n0 + wc * 64 + ni * 16 + l15;
        const float bb = bias[n];
#pragma unroll
        for (int mi = 0; mi < 4; ++mi) {
            const int mbase = m0 + wr * 64 + mi * 16 + lg * 4;
            if (MODE == 2) {
                float* C = (float*)Cv;
#pragma unroll
                for (int j = 0; j < 4; ++j)
                    C[(size_t)(mbase + j) * DM + n] = acc[mi][ni][j] + bb;
            } else if (MODE == 0) {
                unsigned short* C = (unsigned short*)Cv;
                const int h = n >> 6, d = n & 63;
#pragma unroll
                for (int j = 0; j < 4; ++j) {
                    const int m = mbase + j, b = m >> 11, s = m & 2047;
                    C[(((size_t)(b * HH + h)) * SQ + s) * DK + d] =
                        f2bf(acc[mi][ni][j] + bb);
                }
            } else {  // MODE 1: V transposed [B,H,Dk,S]; 4 consecutive s -> 8B store
                unsigned short* C = (unsigned short*)Cv;
                const int h = n >> 6, d = n & 63;
                u16x4 pk;
#pragma unroll
                for (int j = 0; j < 4; ++j) pk[j] = f2bf(acc[mi][ni][j] + bb);
                const int m = mbase, b = m >> 11, s = m & 2047;
                *(u16x4*)&C[(((size_t)(b * HH + h)) * DK + d) * SQ + s] = pk;
            }
        }
    }
}

// ---------------------------------------------------------------------------
// Flash attention, quirk: softmax on UNSCALED scores, /sqrt(Dk)=8 after.
// grid = (S/128, B*H); 4 waves; wave owns 32 q-rows. KV tiles of 128.
// K LDS [128][64], Vt LDS [64][128] staged via global_load_lds with
// pre-swizzled global source; per-wave P tile [32][128] bf16.
// ---------------------------------------------------------------------------
__global__ __launch_bounds__(256, 2)
void flash_attn(const unsigned short* __restrict__ Qb,
                const unsigned short* __restrict__ Kb,
                const unsigned short* __restrict__ Vtb,
                unsigned short* __restrict__ outA)
{
    __shared__ unsigned short Ks[128 * 64];      // 16KB
    __shared__ unsigned short Vs[64 * 128];      // 16KB
    __shared__ unsigned short Ps[4 * 32 * 128];  // 32KB (8KB per wave, private)
    char* Ksb = (char*)Ks;
    char* Vsb = (char*)Vs;

    const int tid = threadIdx.x, lane = tid & 63, wid = tid >> 6;
    const int l15 = lane & 15, lg = lane >> 4;
    const int q0 = blockIdx.x * 128;
    const int bh = blockIdx.y;
    const unsigned short* Qp = Qb + (size_t)bh * SQ * DK;
    const unsigned short* Kp = Kb + (size_t)bh * SQ * DK;
    const unsigned short* Vp = Vtb + (size_t)bh * DK * SQ;
    char* Pwb = (char*)Ps + wid * 8192;

    // Q fragments held in registers for the whole kernel
    bf16x8 qf[2][2];
#pragma unroll
    for (int mi = 0; mi < 2; ++mi)
#pragma unroll
        for (int ki = 0; ki < 2; ++ki)
            qf[mi][ki] = *(const bf16x8*)&Qp[(size_t)(q0 + wid * 32 + mi * 16 + l15) * DK +
                                             ki * 32 + lg * 8];

    f32x4 O[2][4];
    float mrow[2][4], lrow[2][4];
#pragma unroll
    for (int mi = 0; mi < 2; ++mi)
#pragma unroll
        for (int j = 0; j < 4; ++j) { mrow[mi][j] = -3.0e38f; lrow[mi][j] = 0.f; }
#pragma unroll
    for (int mi = 0; mi < 2; ++mi)
#pragma unroll
        for (int di = 0; di < 4; ++di) O[mi][di] = (f32x4){0.f, 0.f, 0.f, 0.f};

    const float L2E = 1.44269504089f;

    for (int kt = 0; kt < 16; ++kt) {
        const int kv0 = kt * 128;
        __syncthreads();  // everyone done reading Ks/Vs from previous tile
        // ---- stage K [128][64] (contiguous) and Vt [64][128] (row chunks) ----
#pragma unroll
        for (int i = 0; i < 4; ++i) {
            const int p = (wid * 4 + i) * 1024 + lane * 16;  // physical LDS byte
            {   // K: logical == global-linear; pre-swizzle the source
                const int Lb = SWZ128(p);
                gll16((const char*)Kp + (size_t)kv0 * 128 + Lb,
                      Ksb + (wid * 4 + i) * 1024);
            }
            {   // Vt: row d = p>>8, 256B per row; global row stride 4096B
                const int d = p >> 8;
                const int cb = (p ^ ((d & 7) << 4)) & 255;
                gll16((const char*)Vp + (size_t)d * 4096 + kv0 * 2 + cb,
                      Vsb + (wid * 4 + i) * 1024);
            }
        }
        asm volatile("s_waitcnt vmcnt(0)" ::: "memory");
        __syncthreads();  // tiles ready

        // ---- S = Q K^T (32 q-rows x 128 kv), f32 acc ----
        f32x4 Sf[2][8];
#pragma unroll
        for (int mi = 0; mi < 2; ++mi)
#pragma unroll
            for (int ni = 0; ni < 8; ++ni) Sf[mi][ni] = (f32x4){0.f, 0.f, 0.f, 0.f};
#pragma unroll
        for (int ki = 0; ki < 2; ++ki) {
#pragma unroll
            for (int ni = 0; ni < 8; ++ni) {
                const int o = (ni * 16 + l15) * 128 + ki * 64 + lg * 16;
                const bf16x8 kf = *(const bf16x8*)(Ksb + SWZ128(o));
                Sf[0][ni] = __builtin_amdgcn_mfma_f32_16x16x32_bf16(qf[0][ki], kf, Sf[0][ni], 0, 0, 0);
                Sf[1][ni] = __builtin_amdgcn_mfma_f32_16x16x32_bf16(qf[1][ki], kf, Sf[1][ni], 0, 0, 0);
            }
        }

        // ---- online softmax (unscaled scores), rows = (lg*4+j) per 16-tile ----
#pragma unroll
        for (int mi = 0; mi < 2; ++mi) {
#pragma unroll
            for (int j = 0; j < 4; ++j) {
                float tm = Sf[mi][0][j];
#pragma unroll
                for (int ni = 1; ni < 8; ++ni) tm = fmaxf(tm, Sf[mi][ni][j]);
#pragma unroll
                for (int d = 1; d < 16; d <<= 1) tm = fmaxf(tm, __shfl_xor(tm, d));
                const float mo = mrow[mi][j];
                const float mn = fmaxf(mo, tm);
                const float corr = __builtin_exp2f((mo - mn) * L2E);
                float rs = 0.f;
#pragma unroll
                for (int ni = 0; ni < 8; ++ni) {
                    const float p = __builtin_exp2f((Sf[mi][ni][j] - mn) * L2E);
                    Sf[mi][ni][j] = p;
                    rs += p;
                }
#pragma unroll
                for (int d = 1; d < 16; d <<= 1) rs += __shfl_xor(rs, d);
                lrow[mi][j] = lrow[mi][j] * corr + rs;
                mrow[mi][j] = mn;
#pragma unroll
                for (int di = 0; di < 4; ++di) O[mi][di][j] *= corr;
            }
        }

        // ---- P -> bf16 -> per-wave LDS (swizzled) ----
#pragma unroll
        for (int mi = 0; mi < 2; ++mi) {
#pragma unroll
            for (int j = 0; j < 4; ++j) {
                const int row = mi * 16 + lg * 4 + j;
#pragma unroll
                for (int ni = 0; ni < 8; ++ni) {
                    const int o = row * 256 + (ni * 16 + l15) * 2;
                    *(unsigned short*)(Pwb + (o ^ ((row & 7) << 4))) = f2bf(Sf[mi][ni][j]);
                }
            }
        }

        // ---- O += P V  (A = P [q x kv], B = V [kv x d] read from Vt) ----
#pragma unroll
        for (int kk = 0; kk < 4; ++kk) {
            bf16x8 pf[2];
#pragma unroll
            for (int mi = 0; mi < 2; ++mi) {
                const int o = (mi * 16 + l15) * 256 + kk * 64 + lg * 16;
                pf[mi] = *(const bf16x8*)(Pwb + SWZ256(o));
            }
#pragma unroll
            for (int di = 0; di < 4; ++di) {
                const int o = (di * 16 + l15) * 256 + kk * 64 + lg * 16;
                const bf16x8 vf = *(const bf16x8*)(Vsb + SWZ256(o));
                O[0][di] = __builtin_amdgcn_mfma_f32_16x16x32_bf16(pf[0], vf, O[0][di], 0, 0, 0);
                O[1][di] = __builtin_amdgcn_mfma_f32_16x16x32_bf16(pf[1], vf, O[1][di], 0, 0, 0);
            }
        }
    }

    // ---- epilogue: out = O / (8 * l); write bf16 [B,S,H*Dk] ----
    const int b = bh >> 4, h = bh & 15;
#pragma unroll
    for (int mi = 0; mi < 2; ++mi) {
#pragma unroll
        for (int j = 0; j < 4; ++j) {
            const float inv = 1.f / (8.f * lrow[mi][j]);
            const int q = q0 + wid * 32 + mi * 16 + lg * 4 + j;
#pragma unroll
            for (int di = 0; di < 4; ++di)
                outA[((size_t)(b * SQ + q)) * DM + h * DK + di * 16 + l15] =
                    f2bf(O[mi][di][j] * inv);
        }
    }
}

// ---------------------------------------------------------------------------
extern "C" void kernel_launch(void* const* d_in, const int* in_sizes, int n_in,
                              void* d_out, int out_size, void* d_ws, size_t ws_size,
                              hipStream_t stream)
{
    (void)in_sizes; (void)n_in; (void)out_size; (void)ws_size;
    const float* q  = (const float*)d_in[0];
    const float* k  = (const float*)d_in[1];
    const float* v  = (const float*)d_in[2];
    const float* WQ = (const float*)d_in[3];
    const float* bQ = (const float*)d_in[4];
    const float* WK = (const float*)d_in[5];
    const float* bK = (const float*)d_in[6];
    const float* WV = (const float*)d_in[7];
    const float* bV = (const float*)d_in[8];
    const float* W0 = (const float*)d_in[9];
    const float* b0 = (const float*)d_in[10];

    unsigned short* ws = (unsigned short*)d_ws;
    const size_t NEL = (size_t)MM * DM;          // 8M elements per buffer
    unsigned short* Qb  = ws;
    unsigned short* Kb  = ws + NEL;
    unsigned short* Vtb = ws + 2 * NEL;
    unsigned short* Ab  = ws + 3 * NEL;          // attention output, bf16 [B,S,D]

    dim3 blk(256);
    dim3 gg(MM / 128, DM / 128);                 // 64 x 8
    hipLaunchKernelGGL((gemm_bt<0>), gg, blk, 0, stream, (const void*)q, WQ, bQ, (void*)Qb);
    hipLaunchKernelGGL((gemm_bt<0>), gg, blk, 0, stream, (const void*)k, WK, bK, (void*)Kb);
    hipLaunchKernelGGL((gemm_bt<1>), gg, blk, 0, stream, (const void*)v, WV, bV, (void*)Vtb);
    hipLaunchKernelGGL(flash_attn, dim3(SQ / 128, BQ * HH), blk, 0, stream, Qb, Kb, Vtb, Ab);
    hipLaunchKernelGGL((gemm_bt<2>), gg, blk, 0, stream, (const void*)Ab, W0, b0, d_out);
}

// Round 6
// 327.796 us; speedup vs baseline: 1.8265x; 1.8265x over previous
//
#include <hip/hip_runtime.h>

typedef __attribute__((ext_vector_type(4))) float f32x4;
typedef __attribute__((ext_vector_type(8))) short bf16x8;
typedef __attribute__((ext_vector_type(8))) unsigned short u16x8;
typedef __attribute__((ext_vector_type(4))) unsigned short u16x4;
typedef __attribute__((ext_vector_type(4))) unsigned int u32x4;

#define DEV static __device__ __forceinline__

// sizes fixed by the problem
#define BQ 4
#define SQ 2048
#define DM 1024
#define HH 16
#define DK 64
#define MM (BQ * SQ)   // 8192

DEV unsigned short f2bf(float f) {
    unsigned int u = __builtin_bit_cast(unsigned int, f);
    u += 0x7fffu + ((u >> 16) & 1u);               // RNE
    return (unsigned short)(u >> 16);
}

DEV unsigned int cvtpk(float lo, float hi) {       // dword = {bf16(lo), bf16(hi)}
    unsigned int r;
    asm("v_cvt_pk_bf16_f32 %0, %1, %2" : "=v"(r) : "v"(lo), "v"(hi));
    return r;
}

DEV void gll16(const void* g, void* l) {           // async global->LDS, 16B/lane
    __builtin_amdgcn_global_load_lds(
        (const __attribute__((address_space(1))) unsigned int*)g,
        (__attribute__((address_space(3))) unsigned int*)l, 16, 0, 0);
}

// swizzles: XOR row bits into byte bits 4.. to break same-bank column reads
#define SWZ64(b)  ((b) ^ ((((b) >> 6) & 3) << 4))   // row stride 64B
#define SWZ128(b) ((b) ^ ((((b) >> 7) & 7) << 4))   // row stride 128B
#define SWZ256(b) ((b) ^ ((((b) >> 8) & 7) << 4))   // row stride 256B

// V column permutation within each 32-block: s = 16a+4b+c  ->  sp = 8b+4a+c.
// Chosen so the PV B-fragment (P) is lane-local after swapped QK^T:
// MFMA k-slot (lg, e) reads permuted col 8*lg+e == original kv 16(e>>2)+4lg+(e&3).

// ---------------------------------------------------------------------------
// C = A @ W^T + bias.  A:[8192x1024] , W:[1024x1024] fp32 row-major.
// MODE 0: A fp32, C bf16 laid out [B,H,S,Dk]        (Q, K)
// MODE 1: A fp32, C bf16 laid out [B,H,Dk,Sperm]    (V transposed, cols permuted)
// MODE 2: A bf16, C fp32 laid out [8192,1024]       (final projection)
// 128x128 tile, BK=32, 4 waves each computing 64x64 via 16x16x32 bf16 MFMA.
// ---------------------------------------------------------------------------
template <int MODE>
__global__ __launch_bounds__(256, 2)
void gemm_bt(const void* __restrict__ Av, const float* __restrict__ Wf,
             const float* __restrict__ bias, void* __restrict__ Cv)
{
    __shared__ unsigned short As[128 * 32];
    __shared__ unsigned short Bs[128 * 32];
    char* Asb = (char*)As;
    char* Bsb = (char*)Bs;

    const int tid = threadIdx.x, lane = tid & 63, wid = tid >> 6;
    const int l15 = lane & 15, lg = lane >> 4;
    const int wr = wid >> 1, wc = wid & 1;
    const int m0 = blockIdx.x * 128, n0 = blockIdx.y * 128;
    const int sr = tid >> 1, sc = (tid & 1) * 16;     // staging row / col-elem

    f32x4 acc[4][4];
#pragma unroll
    for (int i = 0; i < 4; ++i)
#pragma unroll
        for (int j = 0; j < 4; ++j) acc[i][j] = (f32x4){0.f, 0.f, 0.f, 0.f};

    for (int kt = 0; kt < 32; ++kt) {
        const int k0 = kt * 32;
        u16x8 av0, av1, bv0, bv1;
        if (MODE == 2) {
            const unsigned short* Ap =
                (const unsigned short*)Av + (size_t)(m0 + sr) * DM + k0 + sc;
            av0 = *(const u16x8*)Ap;
            av1 = *(const u16x8*)(Ap + 8);
        } else {
            const float* Ap = (const float*)Av + (size_t)(m0 + sr) * DM + k0 + sc;
            f32x4 a0 = *(const f32x4*)Ap,       a1 = *(const f32x4*)(Ap + 4);
            f32x4 a2 = *(const f32x4*)(Ap + 8), a3 = *(const f32x4*)(Ap + 12);
#pragma unroll
            for (int i = 0; i < 4; ++i) {
                av0[i] = f2bf(a0[i]); av0[4 + i] = f2bf(a1[i]);
                av1[i] = f2bf(a2[i]); av1[4 + i] = f2bf(a3[i]);
            }
        }
        {
            const float* Bp = Wf + (size_t)(n0 + sr) * DM + k0 + sc;
            f32x4 b0 = *(const f32x4*)Bp,       b1 = *(const f32x4*)(Bp + 4);
            f32x4 b2 = *(const f32x4*)(Bp + 8), b3 = *(const f32x4*)(Bp + 12);
#pragma unroll
            for (int i = 0; i < 4; ++i) {
                bv0[i] = f2bf(b0[i]); bv0[4 + i] = f2bf(b1[i]);
                bv1[i] = f2bf(b2[i]); bv1[4 + i] = f2bf(b3[i]);
            }
        }
        __syncthreads();                       // prev-iter reads done
        const int lb = sr * 64 + sc * 2;
        *(u16x8*)(Asb + SWZ64(lb))      = av0;
        *(u16x8*)(Asb + SWZ64(lb + 16)) = av1;
        *(u16x8*)(Bsb + SWZ64(lb))      = bv0;
        *(u16x8*)(Bsb + SWZ64(lb + 16)) = bv1;
        __syncthreads();                       // staging visible

        bf16x8 af[4], bfr[4];
#pragma unroll
        for (int mi = 0; mi < 4; ++mi) {
            int o = (wr * 64 + mi * 16 + l15) * 64 + lg * 16;
            af[mi] = *(const bf16x8*)(Asb + SWZ64(o));
        }
#pragma unroll
        for (int ni = 0; ni < 4; ++ni) {
            int o = (wc * 64 + ni * 16 + l15) * 64 + lg * 16;
            bfr[ni] = *(const bf16x8*)(Bsb + SWZ64(o));
        }
#pragma unroll
        for (int mi = 0; mi < 4; ++mi)
#pragma unroll
            for (int ni = 0; ni < 4; ++ni)
                acc[mi][ni] = __builtin_amdgcn_mfma_f32_16x16x32_bf16(
                    af[mi], bfr[ni], acc[mi][ni], 0, 0, 0);
    }

    // epilogue: C row = m0+wr*64+mi*16+lg*4+j, col = n0+wc*64+ni*16+l15
#pragma unroll
    for (int ni = 0; ni < 4; ++ni) {
        const int n = n0 + wc * 64 + ni * 16 + l15;
        const float bb = bias[n];
#pragma unroll
        for (int mi = 0; mi < 4; ++mi) {
            const int mbase = m0 + wr * 64 + mi * 16 + lg * 4;
            if (MODE == 2) {
                float* C = (float*)Cv;
#pragma unroll
                for (int j = 0; j < 4; ++j)
                    C[(size_t)(mbase + j) * DM + n] = acc[mi][ni][j] + bb;
            } else if (MODE == 0) {
                unsigned short* C = (unsigned short*)Cv;
                const int h = n >> 6, d = n & 63;
#pragma unroll
                for (int j = 0; j < 4; ++j) {
                    const int m = mbase + j, b = m >> 11, s = m & 2047;
                    C[(((size_t)(b * HH + h)) * SQ + s) * DK + d] =
                        f2bf(acc[mi][ni][j] + bb);
                }
            } else {  // MODE 1: V^T [B,H,Dk,S] with per-32 column permutation
                unsigned short* C = (unsigned short*)Cv;
                const int h = n >> 6, d = n & 63;
                u16x4 pk;
#pragma unroll
                for (int j = 0; j < 4; ++j) pk[j] = f2bf(acc[mi][ni][j] + bb);
                const int m = mbase, b = m >> 11, s = m & 2047;   // s % 4 == 0
                const int sp = (s & ~31) | (((s >> 2) & 3) << 3) | (((s >> 4) & 1) << 2);
                *(u16x4*)&C[(((size_t)(b * HH + h)) * DK + d) * SQ + sp] = pk;
            }
        }
    }
}

// ---------------------------------------------------------------------------
// Flash attention, quirk: softmax on UNSCALED scores, /sqrt(Dk)=8 after.
// grid = (S/128, B*H); 4 waves; wave owns 32 q-rows. KV tiles of 128.
// Swapped QK^T (S^T = mfma(K,Q)): lane holds q=lane&15, 32 kv values in regs.
//  -> softmax is in-register + 2 shfl_xor; P never touches LDS (lane-local
//     cvt_pk into PV B-fragments thanks to the permuted V^T column layout).
// K and V double-buffered in LDS, prefetch issued before compute (T3 2-phase).
// ---------------------------------------------------------------------------
__global__ __launch_bounds__(256, 2)
void flash_attn(const unsigned short* __restrict__ Qb,
                const unsigned short* __restrict__ Kb,
                const unsigned short* __restrict__ Vtb,
                unsigned short* __restrict__ outA)
{
    __shared__ unsigned short Ks[2][128 * 64];   // 2 x 16KB
    __shared__ unsigned short Vs[2][64 * 128];   // 2 x 16KB

    const int tid = threadIdx.x, lane = tid & 63, wid = tid >> 6;
    const int l15 = lane & 15, lg = lane >> 4;
    const int q0 = blockIdx.x * 128;
    const int bh = blockIdx.y;
    const unsigned short* Qp = Qb + (size_t)bh * SQ * DK;
    const unsigned short* Kp = Kb + (size_t)bh * SQ * DK;
    const unsigned short* Vp = Vtb + (size_t)bh * DK * SQ;

    // Q fragments held in registers for the whole kernel (B-operand layout)
    bf16x8 qf[2][2];
#pragma unroll
    for (int mi = 0; mi < 2; ++mi)
#pragma unroll
        for (int ki = 0; ki < 2; ++ki)
            qf[mi][ki] = *(const bf16x8*)&Qp[(size_t)(q0 + wid * 32 + mi * 16 + l15) * DK +
                                             ki * 32 + lg * 8];

    f32x4 O[2][4];          // O^T: row d = di*16+lg*4+j, col q = mi*16+l15
    float mrun[2], lrun[2]; // per-lane: q = l15 (one q-row per lane per mi)
#pragma unroll
    for (int mi = 0; mi < 2; ++mi) { mrun[mi] = -3.0e38f; lrun[mi] = 0.f; }
#pragma unroll
    for (int mi = 0; mi < 2; ++mi)
#pragma unroll
        for (int di = 0; di < 4; ++di) O[mi][di] = (f32x4){0.f, 0.f, 0.f, 0.f};

    const float L2E = 1.44269504089f;

    // stage one 128-KV tile into buffer BUF (pre-swizzled global source)
#define STAGE(BUF, KV0) do {                                                   \
        char* Ksb_ = (char*)Ks[BUF]; char* Vsb_ = (char*)Vs[BUF];              \
        _Pragma("unroll")                                                      \
        for (int i_ = 0; i_ < 4; ++i_) {                                       \
            const int p_ = (wid * 4 + i_) * 1024 + lane * 16;                  \
            gll16((const char*)Kp + (size_t)(KV0) * 128 + SWZ128(p_),          \
                  Ksb_ + (wid * 4 + i_) * 1024);                               \
            const int d_ = p_ >> 8;                                            \
            const int cb_ = (p_ ^ ((d_ & 7) << 4)) & 255;                      \
            gll16((const char*)Vp + (size_t)d_ * 4096 + (KV0) * 2 + cb_,       \
                  Vsb_ + (wid * 4 + i_) * 1024);                               \
        } } while (0)

    STAGE(0, 0);
    asm volatile("s_waitcnt vmcnt(0)" ::: "memory");
    __syncthreads();

    for (int kt = 0; kt < 16; ++kt) {
        const int cur = kt & 1;
        const char* Ksb = (const char*)Ks[cur];
        const char* Vsb = (const char*)Vs[cur];
        if (kt < 15) STAGE(cur ^ 1, (kt + 1) * 128);   // prefetch next tile

        // ---- S^T = mfma(K, Q): lane holds q=l15, kv = ni*16 + lg*4 + j ----
        f32x4 Sf[2][8];
#pragma unroll
        for (int mi = 0; mi < 2; ++mi)
#pragma unroll
            for (int ni = 0; ni < 8; ++ni) Sf[mi][ni] = (f32x4){0.f, 0.f, 0.f, 0.f};
#pragma unroll
        for (int ki = 0; ki < 2; ++ki) {
#pragma unroll
            for (int ni = 0; ni < 8; ++ni) {
                const int o = (ni * 16 + l15) * 128 + ki * 64 + lg * 16;
                const bf16x8 kf = *(const bf16x8*)(Ksb + SWZ128(o));
                Sf[0][ni] = __builtin_amdgcn_mfma_f32_16x16x32_bf16(kf, qf[0][ki], Sf[0][ni], 0, 0, 0);
                Sf[1][ni] = __builtin_amdgcn_mfma_f32_16x16x32_bf16(kf, qf[1][ki], Sf[1][ni], 0, 0, 0);
            }
        }

        // ---- online softmax: in-register + 2 shfl_xor (unscaled scores) ----
#pragma unroll
        for (int mi = 0; mi < 2; ++mi) {
            float tm = Sf[mi][0][0];
#pragma unroll
            for (int ni = 0; ni < 8; ++ni)
#pragma unroll
                for (int j = 0; j < 4; ++j) tm = fmaxf(tm, Sf[mi][ni][j]);
            tm = fmaxf(tm, __shfl_xor(tm, 16));
            tm = fmaxf(tm, __shfl_xor(tm, 32));
            const float mo = mrun[mi];
            const float mn = fmaxf(mo, tm);
            const float corr = __builtin_amdgcn_exp2f((mo - mn) * L2E);
            float rs = 0.f;
#pragma unroll
            for (int ni = 0; ni < 8; ++ni)
#pragma unroll
                for (int j = 0; j < 4; ++j) {
                    const float p = __builtin_amdgcn_exp2f((Sf[mi][ni][j] - mn) * L2E);
                    Sf[mi][ni][j] = p;
                    rs += p;
                }
            rs += __shfl_xor(rs, 16);
            rs += __shfl_xor(rs, 32);
            lrun[mi] = lrun[mi] * corr + rs;
            mrun[mi] = mn;
#pragma unroll
            for (int di = 0; di < 4; ++di)
#pragma unroll
                for (int j = 0; j < 4; ++j) O[mi][di][j] *= corr;
        }

        // ---- O^T += mfma(V-chunk, P-frag); P fragments are lane-local ----
#pragma unroll
        for (int kk = 0; kk < 4; ++kk) {
            bf16x8 pf[2];
#pragma unroll
            for (int mi = 0; mi < 2; ++mi) {
                u32x4 pd;
                pd[0] = cvtpk(Sf[mi][2 * kk][0],     Sf[mi][2 * kk][1]);
                pd[1] = cvtpk(Sf[mi][2 * kk][2],     Sf[mi][2 * kk][3]);
                pd[2] = cvtpk(Sf[mi][2 * kk + 1][0], Sf[mi][2 * kk + 1][1]);
                pd[3] = cvtpk(Sf[mi][2 * kk + 1][2], Sf[mi][2 * kk + 1][3]);
                pf[mi] = __builtin_bit_cast(bf16x8, pd);
            }
#pragma unroll
            for (int di = 0; di < 4; ++di) {
                const int o = (di * 16 + l15) * 256 + kk * 64 + lg * 16;
                const bf16x8 vf = *(const bf16x8*)(Vsb + SWZ256(o));
                O[0][di] = __builtin_amdgcn_mfma_f32_16x16x32_bf16(vf, pf[0], O[0][di], 0, 0, 0);
                O[1][di] = __builtin_amdgcn_mfma_f32_16x16x32_bf16(vf, pf[1], O[1][di], 0, 0, 0);
            }
        }

        asm volatile("s_waitcnt vmcnt(0)" ::: "memory");  // prefetch landed
        __syncthreads();
    }

    // ---- epilogue: out = O / (8 * l); write bf16 [B,S,H*Dk], 8B stores ----
    const int b = bh >> 4, h = bh & 15;
#pragma unroll
    for (int mi = 0; mi < 2; ++mi) {
        const float inv = 1.f / (8.f * lrun[mi]);
        const int q = q0 + wid * 32 + mi * 16 + l15;
#pragma unroll
        for (int di = 0; di < 4; ++di) {
            u16x4 pk;
#pragma unroll
            for (int j = 0; j < 4; ++j) pk[j] = f2bf(O[mi][di][j] * inv);
            *(u16x4*)&outA[((size_t)(b * SQ + q)) * DM + h * DK + di * 16 + lg * 4] = pk;
        }
    }
#undef STAGE
}

// ---------------------------------------------------------------------------
extern "C" void kernel_launch(void* const* d_in, const int* in_sizes, int n_in,
                              void* d_out, int out_size, void* d_ws, size_t ws_size,
                              hipStream_t stream)
{
    (void)in_sizes; (void)n_in; (void)out_size; (void)ws_size;
    const float* q  = (const float*)d_in[0];
    const float* k  = (const float*)d_in[1];
    const float* v  = (const float*)d_in[2];
    const float* WQ = (const float*)d_in[3];
    const float* bQ = (const float*)d_in[4];
    const float* WK = (const float*)d_in[5];
    const float* bK = (const float*)d_in[6];
    const float* WV = (const float*)d_in[7];
    const float* bV = (const float*)d_in[8];
    const float* W0 = (const float*)d_in[9];
    const float* b0 = (const float*)d_in[10];

    unsigned short* ws = (unsigned short*)d_ws;
    const size_t NEL = (size_t)MM * DM;          // 8M elements per buffer
    unsigned short* Qb  = ws;
    unsigned short* Kb  = ws + NEL;
    unsigned short* Vtb = ws + 2 * NEL;
    unsigned short* Ab  = ws + 3 * NEL;          // attention output, bf16 [B,S,D]

    dim3 blk(256);
    dim3 gg(MM / 128, DM / 128);                 // 64 x 8
    hipLaunchKernelGGL((gemm_bt<0>), gg, blk, 0, stream, (const void*)q, WQ, bQ, (void*)Qb);
    hipLaunchKernelGGL((gemm_bt<0>), gg, blk, 0, stream, (const void*)k, WK, bK, (void*)Kb);
    hipLaunchKernelGGL((gemm_bt<1>), gg, blk, 0, stream, (const void*)v, WV, bV, (void*)Vtb);
    hipLaunchKernelGGL(flash_attn, dim3(SQ / 128, BQ * HH), blk, 0, stream, Qb, Kb, Vtb, Ab);
    hipLaunchKernelGGL((gemm_bt<2>), gg, blk, 0, stream, (const void*)Ab, W0, b0, d_out);
}

// Round 7
// 281.205 us; speedup vs baseline: 2.1291x; 1.1657x over previous
//
#include <hip/hip_runtime.h>

typedef __attribute__((ext_vector_type(4))) float f32x4;
typedef __attribute__((ext_vector_type(8))) short bf16x8;
typedef __attribute__((ext_vector_type(8))) unsigned short u16x8;
typedef __attribute__((ext_vector_type(4))) unsigned short u16x4;
typedef __attribute__((ext_vector_type(4))) unsigned int u32x4;

#define DEV static __device__ __forceinline__

// sizes fixed by the problem
#define BQ 4
#define SQ 2048
#define DM 1024
#define HH 16
#define DK 64
#define MM (BQ * SQ)   // 8192

DEV unsigned short f2bf(float f) {
    unsigned int u = __builtin_bit_cast(unsigned int, f);
    u += 0x7fffu + ((u >> 16) & 1u);               // RNE
    return (unsigned short)(u >> 16);
}

DEV unsigned int cvtpk(float lo, float hi) {       // dword = {bf16(lo), bf16(hi)} (RNE)
    unsigned int r;
    asm("v_cvt_pk_bf16_f32 %0, %1, %2" : "=v"(r) : "v"(lo), "v"(hi));
    return r;
}

DEV void gll16(const void* g, void* l) {           // async global->LDS, 16B/lane
    __builtin_amdgcn_global_load_lds(
        (const __attribute__((address_space(1))) unsigned int*)g,
        (__attribute__((address_space(3))) unsigned int*)l, 16, 0, 0);
}

// swizzles: XOR row bits into byte bits 4.. to break same-bank column reads
#define SWZ64(b)  ((b) ^ ((((b) >> 6) & 3) << 4))   // row stride 64B
#define SWZ128(b) ((b) ^ ((((b) >> 7) & 7) << 4))   // row stride 128B

// pack 16 fp32 (4 x f32x4, K-consecutive) -> 16 bf16 via 8 cvt_pk
DEV u16x8 pack8(const f32x4 a, const f32x4 b) {
    u32x4 d;
    d[0] = cvtpk(a[0], a[1]); d[1] = cvtpk(a[2], a[3]);
    d[2] = cvtpk(b[0], b[1]); d[3] = cvtpk(b[2], b[3]);
    return __builtin_bit_cast(u16x8, d);
}

// V column permutation within each 32-block: s = 16a+4b+c  ->  sp = 8b+4a+c.
// Makes the PV B-fragment (P) lane-local after swapped QK^T:
// MFMA k-slot (lg, e) reads permuted col 8*lg+e == original kv 16(e>>2)+4lg+(e&3).

// ---------------------------------------------------------------------------
// Fused Q/K/V projection: z = blockIdx.z selects input/weight/bias/output.
// C = A @ W^T + bias, A:[8192x1024] fp32, W:[1024x1024] fp32.
// z=0,1 -> bf16 [B,H,S,Dk] (Q, K);  z=2 -> bf16 [B,H,Dk,Sperm] (V^T permuted).
// 128x128 tile, BK=32, 4 waves x 64x64, cvt_pk staging conversion.
// ---------------------------------------------------------------------------
__global__ __launch_bounds__(256, 3)
void gemm_qkv(const float* __restrict__ qv, const float* __restrict__ kv,
              const float* __restrict__ vv,
              const float* __restrict__ WQ, const float* __restrict__ WK,
              const float* __restrict__ WV,
              const float* __restrict__ bQ, const float* __restrict__ bK,
              const float* __restrict__ bV,
              unsigned short* __restrict__ Qb, unsigned short* __restrict__ Kb,
              unsigned short* __restrict__ Vtb)
{
    __shared__ unsigned short As[128 * 32];
    __shared__ unsigned short Bs[128 * 32];
    char* Asb = (char*)As;
    char* Bsb = (char*)Bs;

    const int z = blockIdx.z;
    const float* A    = (z == 0) ? qv : (z == 1) ? kv : vv;
    const float* W    = (z == 0) ? WQ : (z == 1) ? WK : WV;
    const float* bias = (z == 0) ? bQ : (z == 1) ? bK : bV;
    unsigned short* C = (z == 0) ? Qb : (z == 1) ? Kb : Vtb;

    const int tid = threadIdx.x, lane = tid & 63, wid = tid >> 6;
    const int l15 = lane & 15, lg = lane >> 4;
    const int wr = wid >> 1, wc = wid & 1;
    const int m0 = blockIdx.x * 128, n0 = blockIdx.y * 128;
    const int sr = tid >> 1, sc = (tid & 1) * 16;     // staging row / col-elem

    f32x4 acc[4][4];
#pragma unroll
    for (int i = 0; i < 4; ++i)
#pragma unroll
        for (int j = 0; j < 4; ++j) acc[i][j] = (f32x4){0.f, 0.f, 0.f, 0.f};

    for (int kt = 0; kt < 32; ++kt) {
        const int k0 = kt * 32;
        const float* Ap = A + (size_t)(m0 + sr) * DM + k0 + sc;
        const float* Bp = W + (size_t)(n0 + sr) * DM + k0 + sc;
        f32x4 a0 = *(const f32x4*)Ap,       a1 = *(const f32x4*)(Ap + 4);
        f32x4 a2 = *(const f32x4*)(Ap + 8), a3 = *(const f32x4*)(Ap + 12);
        f32x4 b0 = *(const f32x4*)Bp,       b1 = *(const f32x4*)(Bp + 4);
        f32x4 b2 = *(const f32x4*)(Bp + 8), b3 = *(const f32x4*)(Bp + 12);
        const u16x8 av0 = pack8(a0, a1), av1 = pack8(a2, a3);
        const u16x8 bv0 = pack8(b0, b1), bv1 = pack8(b2, b3);

        __syncthreads();                       // prev-iter reads done
        const int lb = sr * 64 + sc * 2;
        *(u16x8*)(Asb + SWZ64(lb))      = av0;
        *(u16x8*)(Asb + SWZ64(lb + 16)) = av1;
        *(u16x8*)(Bsb + SWZ64(lb))      = bv0;
        *(u16x8*)(Bsb + SWZ64(lb + 16)) = bv1;
        __syncthreads();                       // staging visible

        bf16x8 af[4], bfr[4];
#pragma unroll
        for (int mi = 0; mi < 4; ++mi) {
            int o = (wr * 64 + mi * 16 + l15) * 64 + lg * 16;
            af[mi] = *(const bf16x8*)(Asb + SWZ64(o));
        }
#pragma unroll
        for (int ni = 0; ni < 4; ++ni) {
            int o = (wc * 64 + ni * 16 + l15) * 64 + lg * 16;
            bfr[ni] = *(const bf16x8*)(Bsb + SWZ64(o));
        }
        __builtin_amdgcn_s_setprio(1);
#pragma unroll
        for (int mi = 0; mi < 4; ++mi)
#pragma unroll
            for (int ni = 0; ni < 4; ++ni)
                acc[mi][ni] = __builtin_amdgcn_mfma_f32_16x16x32_bf16(
                    af[mi], bfr[ni], acc[mi][ni], 0, 0, 0);
        __builtin_amdgcn_s_setprio(0);
    }

    // epilogue: C row = m0+wr*64+mi*16+lg*4+j, col = n0+wc*64+ni*16+l15
#pragma unroll
    for (int ni = 0; ni < 4; ++ni) {
        const int n = n0 + wc * 64 + ni * 16 + l15;
        const float bb = bias[n];
        const int h = n >> 6, d = n & 63;
#pragma unroll
        for (int mi = 0; mi < 4; ++mi) {
            const int mbase = m0 + wr * 64 + mi * 16 + lg * 4;
            if (z != 2) {                       // [B,H,S,Dk]
#pragma unroll
                for (int j = 0; j < 4; ++j) {
                    const int m = mbase + j, b = m >> 11, s = m & 2047;
                    C[(((size_t)(b * HH + h)) * SQ + s) * DK + d] =
                        f2bf(acc[mi][ni][j] + bb);
                }
            } else {                            // V^T [B,H,Dk,Sperm], 8B stores
                u16x4 pk;
#pragma unroll
                for (int j = 0; j < 4; ++j) pk[j] = f2bf(acc[mi][ni][j] + bb);
                const int m = mbase, b = m >> 11, s = m & 2047;   // s % 4 == 0
                const int sp = (s & ~31) | (((s >> 2) & 3) << 3) | (((s >> 4) & 1) << 2);
                *(u16x4*)&C[(((size_t)(b * HH + h)) * DK + d) * SQ + sp] = pk;
            }
        }
    }
}

// ---------------------------------------------------------------------------
// Output projection: C = A @ W0^T + b0, A bf16 [8192x1024], C fp32.
// ---------------------------------------------------------------------------
__global__ __launch_bounds__(256, 2)
void gemm_out(const unsigned short* __restrict__ Av, const float* __restrict__ Wf,
              const float* __restrict__ bias, float* __restrict__ Cv)
{
    __shared__ unsigned short As[128 * 32];
    __shared__ unsigned short Bs[128 * 32];
    char* Asb = (char*)As;
    char* Bsb = (char*)Bs;

    const int tid = threadIdx.x, lane = tid & 63, wid = tid >> 6;
    const int l15 = lane & 15, lg = lane >> 4;
    const int wr = wid >> 1, wc = wid & 1;
    const int m0 = blockIdx.x * 128, n0 = blockIdx.y * 128;
    const int sr = tid >> 1, sc = (tid & 1) * 16;

    f32x4 acc[4][4];
#pragma unroll
    for (int i = 0; i < 4; ++i)
#pragma unroll
        for (int j = 0; j < 4; ++j) acc[i][j] = (f32x4){0.f, 0.f, 0.f, 0.f};

    for (int kt = 0; kt < 32; ++kt) {
        const int k0 = kt * 32;
        const unsigned short* Ap = Av + (size_t)(m0 + sr) * DM + k0 + sc;
        const u16x8 av0 = *(const u16x8*)Ap;
        const u16x8 av1 = *(const u16x8*)(Ap + 8);
        const float* Bp = Wf + (size_t)(n0 + sr) * DM + k0 + sc;
        f32x4 b0 = *(const f32x4*)Bp,       b1 = *(const f32x4*)(Bp + 4);
        f32x4 b2 = *(const f32x4*)(Bp + 8), b3 = *(const f32x4*)(Bp + 12);
        const u16x8 bv0 = pack8(b0, b1), bv1 = pack8(b2, b3);

        __syncthreads();
        const int lb = sr * 64 + sc * 2;
        *(u16x8*)(Asb + SWZ64(lb))      = av0;
        *(u16x8*)(Asb + SWZ64(lb + 16)) = av1;
        *(u16x8*)(Bsb + SWZ64(lb))      = bv0;
        *(u16x8*)(Bsb + SWZ64(lb + 16)) = bv1;
        __syncthreads();

        bf16x8 af[4], bfr[4];
#pragma unroll
        for (int mi = 0; mi < 4; ++mi) {
            int o = (wr * 64 + mi * 16 + l15) * 64 + lg * 16;
            af[mi] = *(const bf16x8*)(Asb + SWZ64(o));
        }
#pragma unroll
        for (int ni = 0; ni < 4; ++ni) {
            int o = (wc * 64 + ni * 16 + l15) * 64 + lg * 16;
            bfr[ni] = *(const bf16x8*)(Bsb + SWZ64(o));
        }
        __builtin_amdgcn_s_setprio(1);
#pragma unroll
        for (int mi = 0; mi < 4; ++mi)
#pragma unroll
            for (int ni = 0; ni < 4; ++ni)
                acc[mi][ni] = __builtin_amdgcn_mfma_f32_16x16x32_bf16(
                    af[mi], bfr[ni], acc[mi][ni], 0, 0, 0);
        __builtin_amdgcn_s_setprio(0);
    }

#pragma unroll
    for (int ni = 0; ni < 4; ++ni) {
        const int n = n0 + wc * 64 + ni * 16 + l15;
        const float bb = bias[n];
#pragma unroll
        for (int mi = 0; mi < 4; ++mi) {
            const int mbase = m0 + wr * 64 + mi * 16 + lg * 4;
#pragma unroll
            for (int j = 0; j < 4; ++j)
                Cv[(size_t)(mbase + j) * DM + n] = acc[mi][ni][j] + bb;
        }
    }
}

// ---------------------------------------------------------------------------
// Flash attention, quirk: softmax on UNSCALED scores, /sqrt(Dk)=8 after.
// grid = (S/128, B*H); 4 waves; wave owns 32 q-rows. KV tiles of 64,
// K and V double-buffered (32KB LDS -> 4 blocks/CU, 16 waves/CU).
// Swapped QK^T (S^T = mfma(K,Q)): softmax fully in-register (+2 shfl);
// P lane-local via cvt_pk thanks to the permuted V^T column layout.
// T13 defer-max: skip O-rescale when the running max doesn't grow by >8.
// ---------------------------------------------------------------------------
__global__ __launch_bounds__(256, 4)
void flash_attn(const unsigned short* __restrict__ Qb,
                const unsigned short* __restrict__ Kb,
                const unsigned short* __restrict__ Vtb,
                unsigned short* __restrict__ outA)
{
    __shared__ unsigned short Ks[2][64 * 64];    // 2 x 8KB
    __shared__ unsigned short Vs[2][64 * 64];    // 2 x 8KB

    const int tid = threadIdx.x, lane = tid & 63, wid = tid >> 6;
    const int l15 = lane & 15, lg = lane >> 4;
    const int q0 = blockIdx.x * 128;
    const int bh = blockIdx.y;
    const unsigned short* Qp = Qb + (size_t)bh * SQ * DK;
    const unsigned short* Kp = Kb + (size_t)bh * SQ * DK;
    const unsigned short* Vp = Vtb + (size_t)bh * DK * SQ;

    // Q fragments held in registers for the whole kernel (B-operand layout)
    bf16x8 qf[2][2];
#pragma unroll
    for (int mi = 0; mi < 2; ++mi)
#pragma unroll
        for (int ki = 0; ki < 2; ++ki)
            qf[mi][ki] = *(const bf16x8*)&Qp[(size_t)(q0 + wid * 32 + mi * 16 + l15) * DK +
                                             ki * 32 + lg * 8];

    f32x4 O[2][4];          // O^T: row d = di*16+lg*4+j, col q = mi*16+l15
    float mrun[2], lrun[2]; // per-lane q-row = l15
#pragma unroll
    for (int mi = 0; mi < 2; ++mi) { mrun[mi] = -3.0e38f; lrun[mi] = 0.f; }
#pragma unroll
    for (int mi = 0; mi < 2; ++mi)
#pragma unroll
        for (int di = 0; di < 4; ++di) O[mi][di] = (f32x4){0.f, 0.f, 0.f, 0.f};

    const float L2E = 1.44269504089f;

    // stage one 64-KV tile (K [64kv][64d], V^T [64d][64kv]) into buffer BUF
#define STAGE(BUF, KV0) do {                                                   \
        char* Ksb_ = (char*)Ks[BUF]; char* Vsb_ = (char*)Vs[BUF];              \
        _Pragma("unroll")                                                      \
        for (int i_ = 0; i_ < 2; ++i_) {                                       \
            const int p_ = (wid * 2 + i_) * 1024 + lane * 16;                  \
            gll16((const char*)Kp + (size_t)(KV0) * 128 + SWZ128(p_),          \
                  Ksb_ + (wid * 2 + i_) * 1024);                               \
            const int d_ = p_ >> 7;                                            \
            const int cb_ = (p_ ^ ((d_ & 7) << 4)) & 127;                      \
            gll16((const char*)Vp + (size_t)d_ * 4096 + (KV0) * 2 + cb_,       \
                  Vsb_ + (wid * 2 + i_) * 1024);                               \
        } } while (0)

    STAGE(0, 0);
    asm volatile("s_waitcnt vmcnt(0)" ::: "memory");
    __syncthreads();

    for (int kt = 0; kt < 32; ++kt) {
        const int cur = kt & 1;
        const char* Ksb = (const char*)Ks[cur];
        const char* Vsb = (const char*)Vs[cur];
        if (kt < 31) STAGE(cur ^ 1, (kt + 1) * 64);    // prefetch next tile

        // ---- S^T = mfma(K, Q): lane holds q=l15, kv = ni*16 + lg*4 + j ----
        f32x4 Sf[2][4];
#pragma unroll
        for (int mi = 0; mi < 2; ++mi)
#pragma unroll
            for (int ni = 0; ni < 4; ++ni) Sf[mi][ni] = (f32x4){0.f, 0.f, 0.f, 0.f};
        __builtin_amdgcn_s_setprio(1);
#pragma unroll
        for (int ki = 0; ki < 2; ++ki) {
#pragma unroll
            for (int ni = 0; ni < 4; ++ni) {
                const int o = (ni * 16 + l15) * 128 + ki * 64 + lg * 16;
                const bf16x8 kf = *(const bf16x8*)(Ksb + SWZ128(o));
                Sf[0][ni] = __builtin_amdgcn_mfma_f32_16x16x32_bf16(kf, qf[0][ki], Sf[0][ni], 0, 0, 0);
                Sf[1][ni] = __builtin_amdgcn_mfma_f32_16x16x32_bf16(kf, qf[1][ki], Sf[1][ni], 0, 0, 0);
            }
        }
        __builtin_amdgcn_s_setprio(0);

        // ---- online softmax, in-register, defer-max (THR=8) ----
#pragma unroll
        for (int mi = 0; mi < 2; ++mi) {
            float tm = Sf[mi][0][0];
#pragma unroll
            for (int ni = 0; ni < 4; ++ni)
#pragma unroll
                for (int j = 0; j < 4; ++j) tm = fmaxf(tm, Sf[mi][ni][j]);
            tm = fmaxf(tm, __shfl_xor(tm, 16));
            tm = fmaxf(tm, __shfl_xor(tm, 32));
            const float mo = mrun[mi];
            if (__all(tm <= mo + 8.0f)) {       // defer: no rescale, keep mo
                float rs = 0.f;
#pragma unroll
                for (int ni = 0; ni < 4; ++ni)
#pragma unroll
                    for (int j = 0; j < 4; ++j) {
                        const float p = __builtin_amdgcn_exp2f((Sf[mi][ni][j] - mo) * L2E);
                        Sf[mi][ni][j] = p;
                        rs += p;
                    }
                rs += __shfl_xor(rs, 16);
                rs += __shfl_xor(rs, 32);
                lrun[mi] += rs;
            } else {
                const float mn = fmaxf(mo, tm);
                const float corr = __builtin_amdgcn_exp2f((mo - mn) * L2E);
                float rs = 0.f;
#pragma unroll
                for (int ni = 0; ni < 4; ++ni)
#pragma unroll
                    for (int j = 0; j < 4; ++j) {
                        const float p = __builtin_amdgcn_exp2f((Sf[mi][ni][j] - mn) * L2E);
                        Sf[mi][ni][j] = p;
                        rs += p;
                    }
                rs += __shfl_xor(rs, 16);
                rs += __shfl_xor(rs, 32);
                lrun[mi] = lrun[mi] * corr + rs;
                mrun[mi] = mn;
#pragma unroll
                for (int di = 0; di < 4; ++di)
#pragma unroll
                    for (int j = 0; j < 4; ++j) O[mi][di][j] *= corr;
            }
        }

        // ---- O^T += mfma(V-chunk, P-frag); P fragments lane-local ----
#pragma unroll
        for (int kk = 0; kk < 2; ++kk) {
            bf16x8 pf[2];
#pragma unroll
            for (int mi = 0; mi < 2; ++mi) {
                u32x4 pd;
                pd[0] = cvtpk(Sf[mi][2 * kk][0],     Sf[mi][2 * kk][1]);
                pd[1] = cvtpk(Sf[mi][2 * kk][2],     Sf[mi][2 * kk][3]);
                pd[2] = cvtpk(Sf[mi][2 * kk + 1][0], Sf[mi][2 * kk + 1][1]);
                pd[3] = cvtpk(Sf[mi][2 * kk + 1][2], Sf[mi][2 * kk + 1][3]);
                pf[mi] = __builtin_bit_cast(bf16x8, pd);
            }
            __builtin_amdgcn_s_setprio(1);
#pragma unroll
            for (int di = 0; di < 4; ++di) {
                const int o = (di * 16 + l15) * 128 + kk * 64 + lg * 16;
                const bf16x8 vf = *(const bf16x8*)(Vsb + SWZ128(o));
                O[0][di] = __builtin_amdgcn_mfma_f32_16x16x32_bf16(vf, pf[0], O[0][di], 0, 0, 0);
                O[1][di] = __builtin_amdgcn_mfma_f32_16x16x32_bf16(vf, pf[1], O[1][di], 0, 0, 0);
            }
            __builtin_amdgcn_s_setprio(0);
        }

        asm volatile("s_waitcnt vmcnt(0)" ::: "memory");  // prefetch landed
        __syncthreads();
    }

    // ---- epilogue: out = O / (8 * l); write bf16 [B,S,H*Dk], 8B stores ----
    const int b = bh >> 4, h = bh & 15;
#pragma unroll
    for (int mi = 0; mi < 2; ++mi) {
        const float inv = 1.f / (8.f * lrun[mi]);
        const int q = q0 + wid * 32 + mi * 16 + l15;
#pragma unroll
        for (int di = 0; di < 4; ++di) {
            u16x4 pk;
#pragma unroll
            for (int j = 0; j < 4; ++j) pk[j] = f2bf(O[mi][di][j] * inv);
            *(u16x4*)&outA[((size_t)(b * SQ + q)) * DM + h * DK + di * 16 + lg * 4] = pk;
        }
    }
#undef STAGE
}

// ---------------------------------------------------------------------------
extern "C" void kernel_launch(void* const* d_in, const int* in_sizes, int n_in,
                              void* d_out, int out_size, void* d_ws, size_t ws_size,
                              hipStream_t stream)
{
    (void)in_sizes; (void)n_in; (void)out_size; (void)ws_size;
    const float* q  = (const float*)d_in[0];
    const float* k  = (const float*)d_in[1];
    const float* v  = (const float*)d_in[2];
    const float* WQ = (const float*)d_in[3];
    const float* bQ = (const float*)d_in[4];
    const float* WK = (const float*)d_in[5];
    const float* bK = (const float*)d_in[6];
    const float* WV = (const float*)d_in[7];
    const float* bV = (const float*)d_in[8];
    const float* W0 = (const float*)d_in[9];
    const float* b0 = (const float*)d_in[10];

    unsigned short* ws = (unsigned short*)d_ws;
    const size_t NEL = (size_t)MM * DM;          // 8M elements per buffer
    unsigned short* Qb  = ws;
    unsigned short* Kb  = ws + NEL;
    unsigned short* Vtb = ws + 2 * NEL;
    unsigned short* Ab  = ws + 3 * NEL;          // attention output, bf16 [B,S,D]

    dim3 blk(256);
    hipLaunchKernelGGL(gemm_qkv, dim3(MM / 128, DM / 128, 3), blk, 0, stream,
                       q, k, v, WQ, WK, WV, bQ, bK, bV, Qb, Kb, Vtb);
    hipLaunchKernelGGL(flash_attn, dim3(SQ / 128, BQ * HH), blk, 0, stream,
                       Qb, Kb, Vtb, Ab);
    hipLaunchKernelGGL(gemm_out, dim3(MM / 128, DM / 128), blk, 0, stream,
                       Ab, W0, b0, (float*)d_out);
}

// Round 8
// 276.486 us; speedup vs baseline: 2.1654x; 1.0171x over previous
//
#include <hip/hip_runtime.h>

typedef __attribute__((ext_vector_type(4))) float f32x4;
typedef __attribute__((ext_vector_type(8))) short bf16x8;
typedef __attribute__((ext_vector_type(8))) unsigned short u16x8;
typedef __attribute__((ext_vector_type(4))) unsigned short u16x4;
typedef __attribute__((ext_vector_type(4))) unsigned int u32x4;

#define DEV static __device__ __forceinline__

// sizes fixed by the problem
#define BQ 4
#define SQ 2048
#define DM 1024
#define HH 16
#define DK 64
#define MM (BQ * SQ)   // 8192

DEV unsigned short f2bf(float f) {
    unsigned int u = __builtin_bit_cast(unsigned int, f);
    u += 0x7fffu + ((u >> 16) & 1u);               // RNE
    return (unsigned short)(u >> 16);
}

DEV unsigned int cvtpk(float lo, float hi) {       // dword = {bf16(lo), bf16(hi)} (RNE)
    unsigned int r;
    asm("v_cvt_pk_bf16_f32 %0, %1, %2" : "=v"(r) : "v"(lo), "v"(hi));
    return r;
}

DEV void gll16(const void* g, void* l) {           // async global->LDS, 16B/lane
    __builtin_amdgcn_global_load_lds(
        (const __attribute__((address_space(1))) unsigned int*)g,
        (__attribute__((address_space(3))) unsigned int*)l, 16, 0, 0);
}

// raw barrier: NO compiler-inserted vmcnt(0) drain (we count vmcnt manually)
DEV void barrier_nodrain() { asm volatile("s_barrier" ::: "memory"); }

#define SWZ128(b) ((b) ^ ((((b) >> 7) & 7) << 4))   // row stride 128B (flash)

// pack 8 fp32 (2 x f32x4, K-consecutive) -> 8 bf16 via 4 cvt_pk
DEV bf16x8 pack8(const f32x4 a, const f32x4 b) {
    u32x4 d;
    d[0] = cvtpk(a[0], a[1]); d[1] = cvtpk(a[2], a[3]);
    d[2] = cvtpk(b[0], b[1]); d[3] = cvtpk(b[2], b[3]);
    return __builtin_bit_cast(bf16x8, d);
}

// V column permutation within each 32-block: s = 16a+4b+c  ->  sp = 8b+4a+c.
// Makes the PV B-fragment (P) lane-local after swapped QK^T in flash_attn.

// ---------------------------------------------------------------------------
// Fused Q/K/V projection, T3/T4 pipeline.
// C = A @ W^T + bias, A:[8192x1024] fp32, W:[1024x1024] fp32.
// z=0,1 -> bf16 [B,H,S,Dk] (Q, K);  z=2 -> bf16 [B,H,Dk,Sperm] (V^T permuted).
// 128x128 tile, BK=32. A/W staged as RAW FP32 via global_load_lds
// (pre-swizzled per-lane source, linear LDS dest, swizzled reads),
// double-buffered, counted vmcnt(8), raw s_barrier (no drain).
// fp32->bf16 conversion happens at fragment-read time (cvt_pk).
// LDS = 2 x (16K + 16K) = 64KB -> 2 blocks/CU.
// fp32 tile swizzle (128B rows, 8 slots): slot ^= (row & 7).
// ---------------------------------------------------------------------------
__global__ __launch_bounds__(256, 2)
void gemm_qkv(const float* __restrict__ qv, const float* __restrict__ kv,
              const float* __restrict__ vv,
              const float* __restrict__ WQ, const float* __restrict__ WK,
              const float* __restrict__ WV,
              const float* __restrict__ bQ, const float* __restrict__ bK,
              const float* __restrict__ bV,
              unsigned short* __restrict__ Qb, unsigned short* __restrict__ Kb,
              unsigned short* __restrict__ Vtb)
{
    __shared__ char Asb[2][16384];
    __shared__ char Bsb[2][16384];

    const int z = blockIdx.z;
    const float* A    = (z == 0) ? qv : (z == 1) ? kv : vv;
    const float* W    = (z == 0) ? WQ : (z == 1) ? WK : WV;
    const float* bias = (z == 0) ? bQ : (z == 1) ? bK : bV;
    unsigned short* C = (z == 0) ? Qb : (z == 1) ? Kb : Vtb;

    const int tid = threadIdx.x, lane = tid & 63, wid = tid >> 6;
    const int l15 = lane & 15, lg = lane >> 4;
    const int wr = wid >> 1, wc = wid & 1;
    const int m0 = blockIdx.x * 128, n0 = blockIdx.y * 128;

    f32x4 acc[4][4];
#pragma unroll
    for (int i = 0; i < 4; ++i)
#pragma unroll
        for (int j = 0; j < 4; ++j) acc[i][j] = (f32x4){0.f, 0.f, 0.f, 0.f};

    // stage one BK=32 fp32 K-slab of A and W into buffer BUF (8 gll16/thread)
#define STAGE_QKV(BUF, K0) do {                                                \
        _Pragma("unroll")                                                      \
        for (int i_ = 0; i_ < 4; ++i_) {                                       \
            const int p_ = i_ * 4096 + tid * 16;                               \
            const int r_ = p_ >> 7;                                            \
            const int sl_ = (((p_ >> 4) & 7) ^ (r_ & 7)) << 4;                 \
            gll16((const char*)A + (size_t)(m0 + r_) * 4096 + (K0) * 4 + sl_,  \
                  Asb[BUF] + i_ * 4096 + wid * 1024);                          \
            gll16((const char*)W + (size_t)(n0 + r_) * 4096 + (K0) * 4 + sl_,  \
                  Bsb[BUF] + i_ * 4096 + wid * 1024);                          \
        } } while (0)

    STAGE_QKV(0, 0);

    for (int kt = 0; kt < 32; ++kt) {
        const int cur = kt & 1;
        if (kt < 31) {
            STAGE_QKV(cur ^ 1, (kt + 1) * 32);
            asm volatile("s_waitcnt vmcnt(8)" ::: "memory");  // cur tile landed
        } else {
            asm volatile("s_waitcnt vmcnt(0)" ::: "memory");
        }
        barrier_nodrain();

        const char* Ac = Asb[cur];
        const char* Bc = Bsb[cur];
        bf16x8 af[4], bfr[4];
#pragma unroll
        for (int mi = 0; mi < 4; ++mi) {
            const int r = wr * 64 + mi * 16 + l15, sw = r & 7;
            const f32x4 lo = *(const f32x4*)(Ac + r * 128 + (((2 * lg)     ^ sw) << 4));
            const f32x4 hi = *(const f32x4*)(Ac + r * 128 + (((2 * lg + 1) ^ sw) << 4));
            af[mi] = pack8(lo, hi);
        }
#pragma unroll
        for (int ni = 0; ni < 4; ++ni) {
            const int r = wc * 64 + ni * 16 + l15, sw = r & 7;
            const f32x4 lo = *(const f32x4*)(Bc + r * 128 + (((2 * lg)     ^ sw) << 4));
            const f32x4 hi = *(const f32x4*)(Bc + r * 128 + (((2 * lg + 1) ^ sw) << 4));
            bfr[ni] = pack8(lo, hi);
        }
        __builtin_amdgcn_s_setprio(1);
#pragma unroll
        for (int mi = 0; mi < 4; ++mi)
#pragma unroll
            for (int ni = 0; ni < 4; ++ni)
                acc[mi][ni] = __builtin_amdgcn_mfma_f32_16x16x32_bf16(
                    af[mi], bfr[ni], acc[mi][ni], 0, 0, 0);
        __builtin_amdgcn_s_setprio(0);
        barrier_nodrain();   // reads done before next STAGE overwrites cur
    }
#undef STAGE_QKV

    // epilogue: C row = m0+wr*64+mi*16+lg*4+j, col = n0+wc*64+ni*16+l15
#pragma unroll
    for (int ni = 0; ni < 4; ++ni) {
        const int n = n0 + wc * 64 + ni * 16 + l15;
        const float bb = bias[n];
        const int h = n >> 6, d = n & 63;
#pragma unroll
        for (int mi = 0; mi < 4; ++mi) {
            const int mbase = m0 + wr * 64 + mi * 16 + lg * 4;
            if (z != 2) {                       // [B,H,S,Dk]
#pragma unroll
                for (int j = 0; j < 4; ++j) {
                    const int m = mbase + j, b = m >> 11, s = m & 2047;
                    C[(((size_t)(b * HH + h)) * SQ + s) * DK + d] =
                        f2bf(acc[mi][ni][j] + bb);
                }
            } else {                            // V^T [B,H,Dk,Sperm], 8B stores
                u16x4 pk;
#pragma unroll
                for (int j = 0; j < 4; ++j) pk[j] = f2bf(acc[mi][ni][j] + bb);
                const int m = mbase, b = m >> 11, s = m & 2047;   // s % 4 == 0
                const int sp = (s & ~31) | (((s >> 2) & 3) << 3) | (((s >> 4) & 1) << 2);
                *(u16x4*)&C[(((size_t)(b * HH + h)) * DK + d) * SQ + sp] = pk;
            }
        }
    }
}

// ---------------------------------------------------------------------------
// Output projection, same T3/T4 pipeline. A bf16 [8192x1024], C fp32.
// A staged bf16 via gll16 (64B rows, slot ^= (row>>1)&3); W staged fp32.
// LDS = 2 x (8K + 16K) = 48KB -> 3 blocks/CU. vmcnt(6).
// ---------------------------------------------------------------------------
__global__ __launch_bounds__(256, 3)
void gemm_out(const unsigned short* __restrict__ Av, const float* __restrict__ Wf,
              const float* __restrict__ bias, float* __restrict__ Cv)
{
    __shared__ char Asb[2][8192];
    __shared__ char Bsb[2][16384];

    const int tid = threadIdx.x, lane = tid & 63, wid = tid >> 6;
    const int l15 = lane & 15, lg = lane >> 4;
    const int wr = wid >> 1, wc = wid & 1;
    const int m0 = blockIdx.x * 128, n0 = blockIdx.y * 128;

    f32x4 acc[4][4];
#pragma unroll
    for (int i = 0; i < 4; ++i)
#pragma unroll
        for (int j = 0; j < 4; ++j) acc[i][j] = (f32x4){0.f, 0.f, 0.f, 0.f};

#define STAGE_OUT(BUF, K0) do {                                                \
        _Pragma("unroll")                                                      \
        for (int i_ = 0; i_ < 2; ++i_) {                                       \
            const int p_ = i_ * 4096 + tid * 16;                               \
            const int r_ = p_ >> 6;                                            \
            const int sl_ = ((((p_ >> 4) & 3) ^ ((r_ >> 1) & 3)) << 4);        \
            gll16((const char*)Av + (size_t)(m0 + r_) * 2048 + (K0) * 2 + sl_, \
                  Asb[BUF] + i_ * 4096 + wid * 1024);                          \
        }                                                                      \
        _Pragma("unroll")                                                      \
        for (int i_ = 0; i_ < 4; ++i_) {                                       \
            const int p_ = i_ * 4096 + tid * 16;                               \
            const int r_ = p_ >> 7;                                            \
            const int sl_ = (((p_ >> 4) & 7) ^ (r_ & 7)) << 4;                 \
            gll16((const char*)Wf + (size_t)(n0 + r_) * 4096 + (K0) * 4 + sl_, \
                  Bsb[BUF] + i_ * 4096 + wid * 1024);                          \
        } } while (0)

    STAGE_OUT(0, 0);

    for (int kt = 0; kt < 32; ++kt) {
        const int cur = kt & 1;
        if (kt < 31) {
            STAGE_OUT(cur ^ 1, (kt + 1) * 32);
            asm volatile("s_waitcnt vmcnt(6)" ::: "memory");
        } else {
            asm volatile("s_waitcnt vmcnt(0)" ::: "memory");
        }
        barrier_nodrain();

        const char* Ac = Asb[cur];
        const char* Bc = Bsb[cur];
        bf16x8 af[4], bfr[4];
#pragma unroll
        for (int mi = 0; mi < 4; ++mi) {
            const int r = wr * 64 + mi * 16 + l15;
            af[mi] = *(const bf16x8*)(Ac + r * 64 + ((lg ^ ((r >> 1) & 3)) << 4));
        }
#pragma unroll
        for (int ni = 0; ni < 4; ++ni) {
            const int r = wc * 64 + ni * 16 + l15, sw = r & 7;
            const f32x4 lo = *(const f32x4*)(Bc + r * 128 + (((2 * lg)     ^ sw) << 4));
            const f32x4 hi = *(const f32x4*)(Bc + r * 128 + (((2 * lg + 1) ^ sw) << 4));
            bfr[ni] = pack8(lo, hi);
        }
        __builtin_amdgcn_s_setprio(1);
#pragma unroll
        for (int mi = 0; mi < 4; ++mi)
#pragma unroll
            for (int ni = 0; ni < 4; ++ni)
                acc[mi][ni] = __builtin_amdgcn_mfma_f32_16x16x32_bf16(
                    af[mi], bfr[ni], acc[mi][ni], 0, 0, 0);
        __builtin_amdgcn_s_setprio(0);
        barrier_nodrain();
    }
#undef STAGE_OUT

#pragma unroll
    for (int ni = 0; ni < 4; ++ni) {
        const int n = n0 + wc * 64 + ni * 16 + l15;
        const float bb = bias[n];
#pragma unroll
        for (int mi = 0; mi < 4; ++mi) {
            const int mbase = m0 + wr * 64 + mi * 16 + lg * 4;
#pragma unroll
            for (int j = 0; j < 4; ++j)
                Cv[(size_t)(mbase + j) * DM + n] = acc[mi][ni][j] + bb;
        }
    }
}

// ---------------------------------------------------------------------------
// Flash attention (unchanged this round), quirk: softmax on UNSCALED scores,
// /sqrt(Dk)=8 after. grid = (S/128, B*H); 4 waves; KV tiles of 64, dbuf.
// Swapped QK^T; softmax in-register; P lane-local via permuted V^T.
// ---------------------------------------------------------------------------
__global__ __launch_bounds__(256, 4)
void flash_attn(const unsigned short* __restrict__ Qb,
                const unsigned short* __restrict__ Kb,
                const unsigned short* __restrict__ Vtb,
                unsigned short* __restrict__ outA)
{
    __shared__ unsigned short Ks[2][64 * 64];    // 2 x 8KB
    __shared__ unsigned short Vs[2][64 * 64];    // 2 x 8KB

    const int tid = threadIdx.x, lane = tid & 63, wid = tid >> 6;
    const int l15 = lane & 15, lg = lane >> 4;
    const int q0 = blockIdx.x * 128;
    const int bh = blockIdx.y;
    const unsigned short* Qp = Qb + (size_t)bh * SQ * DK;
    const unsigned short* Kp = Kb + (size_t)bh * SQ * DK;
    const unsigned short* Vp = Vtb + (size_t)bh * DK * SQ;

    bf16x8 qf[2][2];
#pragma unroll
    for (int mi = 0; mi < 2; ++mi)
#pragma unroll
        for (int ki = 0; ki < 2; ++ki)
            qf[mi][ki] = *(const bf16x8*)&Qp[(size_t)(q0 + wid * 32 + mi * 16 + l15) * DK +
                                             ki * 32 + lg * 8];

    f32x4 O[2][4];          // O^T: row d = di*16+lg*4+j, col q = mi*16+l15
    float mrun[2], lrun[2];
#pragma unroll
    for (int mi = 0; mi < 2; ++mi) { mrun[mi] = -3.0e38f; lrun[mi] = 0.f; }
#pragma unroll
    for (int mi = 0; mi < 2; ++mi)
#pragma unroll
        for (int di = 0; di < 4; ++di) O[mi][di] = (f32x4){0.f, 0.f, 0.f, 0.f};

    const float L2E = 1.44269504089f;

#define STAGE(BUF, KV0) do {                                                   \
        char* Ksb_ = (char*)Ks[BUF]; char* Vsb_ = (char*)Vs[BUF];              \
        _Pragma("unroll")                                                      \
        for (int i_ = 0; i_ < 2; ++i_) {                                       \
            const int p_ = (wid * 2 + i_) * 1024 + lane * 16;                  \
            gll16((const char*)Kp + (size_t)(KV0) * 128 + SWZ128(p_),          \
                  Ksb_ + (wid * 2 + i_) * 1024);                               \
            const int d_ = p_ >> 7;                                            \
            const int cb_ = (p_ ^ ((d_ & 7) << 4)) & 127;                      \
            gll16((const char*)Vp + (size_t)d_ * 4096 + (KV0) * 2 + cb_,       \
                  Vsb_ + (wid * 2 + i_) * 1024);                               \
        } } while (0)

    STAGE(0, 0);
    asm volatile("s_waitcnt vmcnt(0)" ::: "memory");
    __syncthreads();

    for (int kt = 0; kt < 32; ++kt) {
        const int cur = kt & 1;
        const char* Ksb = (const char*)Ks[cur];
        const char* Vsb = (const char*)Vs[cur];
        if (kt < 31) STAGE(cur ^ 1, (kt + 1) * 64);    // prefetch next tile

        f32x4 Sf[2][4];
#pragma unroll
        for (int mi = 0; mi < 2; ++mi)
#pragma unroll
            for (int ni = 0; ni < 4; ++ni) Sf[mi][ni] = (f32x4){0.f, 0.f, 0.f, 0.f};
        __builtin_amdgcn_s_setprio(1);
#pragma unroll
        for (int ki = 0; ki < 2; ++ki) {
#pragma unroll
            for (int ni = 0; ni < 4; ++ni) {
                const int o = (ni * 16 + l15) * 128 + ki * 64 + lg * 16;
                const bf16x8 kf = *(const bf16x8*)(Ksb + SWZ128(o));
                Sf[0][ni] = __builtin_amdgcn_mfma_f32_16x16x32_bf16(kf, qf[0][ki], Sf[0][ni], 0, 0, 0);
                Sf[1][ni] = __builtin_amdgcn_mfma_f32_16x16x32_bf16(kf, qf[1][ki], Sf[1][ni], 0, 0, 0);
            }
        }
        __builtin_amdgcn_s_setprio(0);

#pragma unroll
        for (int mi = 0; mi < 2; ++mi) {
            float tm = Sf[mi][0][0];
#pragma unroll
            for (int ni = 0; ni < 4; ++ni)
#pragma unroll
                for (int j = 0; j < 4; ++j) tm = fmaxf(tm, Sf[mi][ni][j]);
            tm = fmaxf(tm, __shfl_xor(tm, 16));
            tm = fmaxf(tm, __shfl_xor(tm, 32));
            const float mo = mrun[mi];
            if (__all(tm <= mo + 8.0f)) {       // defer: no rescale, keep mo
                float rs = 0.f;
#pragma unroll
                for (int ni = 0; ni < 4; ++ni)
#pragma unroll
                    for (int j = 0; j < 4; ++j) {
                        const float p = __builtin_amdgcn_exp2f((Sf[mi][ni][j] - mo) * L2E);
                        Sf[mi][ni][j] = p;
                        rs += p;
                    }
                rs += __shfl_xor(rs, 16);
                rs += __shfl_xor(rs, 32);
                lrun[mi] += rs;
            } else {
                const float mn = fmaxf(mo, tm);
                const float corr = __builtin_amdgcn_exp2f((mo - mn) * L2E);
                float rs = 0.f;
#pragma unroll
                for (int ni = 0; ni < 4; ++ni)
#pragma unroll
                    for (int j = 0; j < 4; ++j) {
                        const float p = __builtin_amdgcn_exp2f((Sf[mi][ni][j] - mn) * L2E);
                        Sf[mi][ni][j] = p;
                        rs += p;
                    }
                rs += __shfl_xor(rs, 16);
                rs += __shfl_xor(rs, 32);
                lrun[mi] = lrun[mi] * corr + rs;
                mrun[mi] = mn;
#pragma unroll
                for (int di = 0; di < 4; ++di)
#pragma unroll
                    for (int j = 0; j < 4; ++j) O[mi][di][j] *= corr;
            }
        }

#pragma unroll
        for (int kk = 0; kk < 2; ++kk) {
            bf16x8 pf[2];
#pragma unroll
            for (int mi = 0; mi < 2; ++mi) {
                u32x4 pd;
                pd[0] = cvtpk(Sf[mi][2 * kk][0],     Sf[mi][2 * kk][1]);
                pd[1] = cvtpk(Sf[mi][2 * kk][2],     Sf[mi][2 * kk][3]);
                pd[2] = cvtpk(Sf[mi][2 * kk + 1][0], Sf[mi][2 * kk + 1][1]);
                pd[3] = cvtpk(Sf[mi][2 * kk + 1][2], Sf[mi][2 * kk + 1][3]);
                pf[mi] = __builtin_bit_cast(bf16x8, pd);
            }
            __builtin_amdgcn_s_setprio(1);
#pragma unroll
            for (int di = 0; di < 4; ++di) {
                const int o = (di * 16 + l15) * 128 + kk * 64 + lg * 16;
                const bf16x8 vf = *(const bf16x8*)(Vsb + SWZ128(o));
                O[0][di] = __builtin_amdgcn_mfma_f32_16x16x32_bf16(vf, pf[0], O[0][di], 0, 0, 0);
                O[1][di] = __builtin_amdgcn_mfma_f32_16x16x32_bf16(vf, pf[1], O[1][di], 0, 0, 0);
            }
            __builtin_amdgcn_s_setprio(0);
        }

        asm volatile("s_waitcnt vmcnt(0)" ::: "memory");  // prefetch landed
        __syncthreads();
    }

    const int b = bh >> 4, h = bh & 15;
#pragma unroll
    for (int mi = 0; mi < 2; ++mi) {
        const float inv = 1.f / (8.f * lrun[mi]);
        const int q = q0 + wid * 32 + mi * 16 + l15;
#pragma unroll
        for (int di = 0; di < 4; ++di) {
            u16x4 pk;
#pragma unroll
            for (int j = 0; j < 4; ++j) pk[j] = f2bf(O[mi][di][j] * inv);
            *(u16x4*)&outA[((size_t)(b * SQ + q)) * DM + h * DK + di * 16 + lg * 4] = pk;
        }
    }
#undef STAGE
}

// ---------------------------------------------------------------------------
extern "C" void kernel_launch(void* const* d_in, const int* in_sizes, int n_in,
                              void* d_out, int out_size, void* d_ws, size_t ws_size,
                              hipStream_t stream)
{
    (void)in_sizes; (void)n_in; (void)out_size; (void)ws_size;
    const float* q  = (const float*)d_in[0];
    const float* k  = (const float*)d_in[1];
    const float* v  = (const float*)d_in[2];
    const float* WQ = (const float*)d_in[3];
    const float* bQ = (const float*)d_in[4];
    const float* WK = (const float*)d_in[5];
    const float* bK = (const float*)d_in[6];
    const float* WV = (const float*)d_in[7];
    const float* bV = (const float*)d_in[8];
    const float* W0 = (const float*)d_in[9];
    const float* b0 = (const float*)d_in[10];

    unsigned short* ws = (unsigned short*)d_ws;
    const size_t NEL = (size_t)MM * DM;          // 8M elements per buffer
    unsigned short* Qb  = ws;
    unsigned short* Kb  = ws + NEL;
    unsigned short* Vtb = ws + 2 * NEL;
    unsigned short* Ab  = ws + 3 * NEL;          // attention output, bf16 [B,S,D]

    dim3 blk(256);
    hipLaunchKernelGGL(gemm_qkv, dim3(MM / 128, DM / 128, 3), blk, 0, stream,
                       q, k, v, WQ, WK, WV, bQ, bK, bV, Qb, Kb, Vtb);
    hipLaunchKernelGGL(flash_attn, dim3(SQ / 128, BQ * HH), blk, 0, stream,
                       Qb, Kb, Vtb, Ab);
    hipLaunchKernelGGL(gemm_out, dim3(MM / 128, DM / 128), blk, 0, stream,
                       Ab, W0, b0, (float*)d_out);
}

// Round 9
// 255.549 us; speedup vs baseline: 2.3429x; 1.0819x over previous
//
#include <hip/hip_runtime.h>

typedef __attribute__((ext_vector_type(4))) float f32x4;
typedef __attribute__((ext_vector_type(8))) short bf16x8;
typedef __attribute__((ext_vector_type(8))) unsigned short u16x8;
typedef __attribute__((ext_vector_type(4))) unsigned short u16x4;
typedef __attribute__((ext_vector_type(4))) unsigned int u32x4;

#define DEV static __device__ __forceinline__

// sizes fixed by the problem
#define BQ 4
#define SQ 2048
#define DM 1024
#define HH 16
#define DK 64
#define MM (BQ * SQ)   // 8192

DEV unsigned short f2bf(float f) {
    unsigned int u = __builtin_bit_cast(unsigned int, f);
    u += 0x7fffu + ((u >> 16) & 1u);               // RNE
    return (unsigned short)(u >> 16);
}

DEV unsigned int cvtpk(float lo, float hi) {       // dword = {bf16(lo), bf16(hi)} (RNE)
    unsigned int r;
    asm("v_cvt_pk_bf16_f32 %0, %1, %2" : "=v"(r) : "v"(lo), "v"(hi));
    return r;
}

DEV void gll16(const void* g, void* l) {           // async global->LDS, 16B/lane
    __builtin_amdgcn_global_load_lds(
        (const __attribute__((address_space(1))) unsigned int*)g,
        (__attribute__((address_space(3))) unsigned int*)l, 16, 0, 0);
}

#define SWZ128(b) ((b) ^ ((((b) >> 7) & 7) << 4))   // row stride 128B (flash)

// pack 8 fp32 (2 x f32x4, K-consecutive) -> 8 bf16 via 4 cvt_pk
DEV u16x8 pack8(const f32x4 a, const f32x4 b) {
    u32x4 d;
    d[0] = cvtpk(a[0], a[1]); d[1] = cvtpk(a[2], a[3]);
    d[2] = cvtpk(b[0], b[1]); d[3] = cvtpk(b[2], b[3]);
    return __builtin_bit_cast(u16x8, d);
}

// ---------------------------------------------------------------------------
// fp32 -> bf16 (RNE) conversion pre-pass for q,k,v and the four weights.
// 8 elems per thread-iteration, fully coalesced. ~168MB traffic.
// Segments in 8-elem units: q,k,v = 2^20 each; WQ,WK,WV,W0 = 2^17 each.
// ---------------------------------------------------------------------------
__global__ __launch_bounds__(256)
void conv_bf16(const float* __restrict__ q, const float* __restrict__ k,
               const float* __restrict__ v,
               const float* __restrict__ WQ, const float* __restrict__ WK,
               const float* __restrict__ WV, const float* __restrict__ W0,
               unsigned short* __restrict__ qb, unsigned short* __restrict__ kb,
               unsigned short* __restrict__ vb,
               unsigned short* __restrict__ wq, unsigned short* __restrict__ wk,
               unsigned short* __restrict__ wv, unsigned short* __restrict__ w0)
{
    const unsigned int NA = 1u << 20, NW = 1u << 17;
    const unsigned int total = 3 * NA + 4 * NW;    // 3,670,016 units
    for (unsigned int idx = blockIdx.x * 256 + threadIdx.x; idx < total;
         idx += gridDim.x * 256) {
        const float* src;
        unsigned short* dst;
        unsigned int off;
        if (idx < 3 * NA) {
            const unsigned int s = idx >> 20;
            off = idx & (NA - 1);
            src = (s == 0) ? q : (s == 1) ? k : v;
            dst = (s == 0) ? qb : (s == 1) ? kb : vb;
        } else {
            const unsigned int r = idx - 3 * NA, s = r >> 17;
            off = r & (NW - 1);
            src = (s == 0) ? WQ : (s == 1) ? WK : (s == 2) ? WV : W0;
            dst = (s == 0) ? wq : (s == 1) ? wk : (s == 2) ? wv : w0;
        }
        const f32x4 a = *(const f32x4*)(src + (size_t)off * 8);
        const f32x4 b = *(const f32x4*)(src + (size_t)off * 8 + 4);
        *(u16x8*)(dst + (size_t)off * 8) = pack8(a, b);
    }
}

// ---------------------------------------------------------------------------
// m97-structure bf16 GEMM core (shared by qkv and out):
// C = A @ W^T (+bias in epilogue). A,W bf16 row-major [rows][1024].
// 128x128 tile, BK=64, 4 waves x 64x64, single 32KB LDS buffer,
// global_load_lds width-16 both operands with granule-XOR swizzle
// (pre-swizzled global SOURCE, linear LDS dest, swizzled reads — rule 21),
// two __syncthreads per K-step (compiler-drained; proven 874 TF shape).
// LDS tile: [128 rows][8 granules of 16B]; phys granule p of row r holds
// global granule p ^ (r&7)  (involution).
// ---------------------------------------------------------------------------
#define GEMM_CORE(Ap, Wp)                                                      \
    f32x4 acc[4][4];                                                           \
    _Pragma("unroll")                                                          \
    for (int i = 0; i < 4; ++i)                                                \
        _Pragma("unroll")                                                      \
        for (int j = 0; j < 4; ++j) acc[i][j] = (f32x4){0.f, 0.f, 0.f, 0.f};   \
    for (int kt = 0; kt < 16; ++kt) {                                          \
        __syncthreads();                       /* prev-step reads done */      \
        _Pragma("unroll")                                                      \
        for (int i_ = 0; i_ < 4; ++i_) {                                       \
            const int r_ = i_ * 32 + wid * 8 + (lane >> 3);                    \
            const int g_ = (lane & 7) ^ (r_ & 7);                              \
            gll16(Ap + (size_t)(m0 + r_) * 1024 + kt * 64 + g_ * 8,            \
                  Asb + i_ * 4096 + wid * 1024);                               \
            gll16(Wp + (size_t)(n0 + r_) * 1024 + kt * 64 + g_ * 8,            \
                  Bsb + i_ * 4096 + wid * 1024);                               \
        }                                                                      \
        __syncthreads();                       /* drains vmcnt -> visible */   \
        _Pragma("unroll")                                                      \
        for (int ki = 0; ki < 2; ++ki) {                                       \
            bf16x8 af[4], bw[4];                                               \
            _Pragma("unroll")                                                  \
            for (int mi = 0; mi < 4; ++mi) {                                   \
                const int r = wr * 64 + mi * 16 + l15;                         \
                const int p = (ki * 4 + lg) ^ (r & 7);                         \
                af[mi] = *(const bf16x8*)(Asb + r * 128 + p * 16);             \
            }                                                                  \
            _Pragma("unroll")                                                  \
            for (int ni = 0; ni < 4; ++ni) {                                   \
                const int r = wc * 64 + ni * 16 + l15;                         \
                const int p = (ki * 4 + lg) ^ (r & 7);                         \
                bw[ni] = *(const bf16x8*)(Bsb + r * 128 + p * 16);             \
            }                                                                  \
            _Pragma("unroll")                                                  \
            for (int mi = 0; mi < 4; ++mi)                                     \
                _Pragma("unroll")                                              \
                for (int ni = 0; ni < 4; ++ni)                                 \
                    acc[mi][ni] = __builtin_amdgcn_mfma_f32_16x16x32_bf16(     \
                        af[mi], bw[ni], acc[mi][ni], 0, 0, 0);                 \
        }                                                                      \
    }

// Fused Q/K/V projection: blockIdx.z selects input/weight/bias/output.
// z=0,1 -> bf16 [B,H,S,Dk] (Q,K); z=2 -> bf16 [B,H,Dk,Sperm] (V^T permuted:
// s = 16a+4b+c -> sp = 8b+4a+c within each 32-block, making flash's PV
// B-fragment lane-local after swapped QK^T).
__global__ __launch_bounds__(256, 3)
void gemm_qkv(const unsigned short* __restrict__ qb,
              const unsigned short* __restrict__ kb,
              const unsigned short* __restrict__ vb,
              const unsigned short* __restrict__ wq,
              const unsigned short* __restrict__ wk,
              const unsigned short* __restrict__ wv,
              const float* __restrict__ bQ, const float* __restrict__ bK,
              const float* __restrict__ bV,
              unsigned short* __restrict__ Qb, unsigned short* __restrict__ Kb,
              unsigned short* __restrict__ Vtb)
{
    __shared__ char Asb[16384];
    __shared__ char Bsb[16384];

    const int z = blockIdx.z;
    const unsigned short* A = (z == 0) ? qb : (z == 1) ? kb : vb;
    const unsigned short* W = (z == 0) ? wq : (z == 1) ? wk : wv;
    const float* bias       = (z == 0) ? bQ : (z == 1) ? bK : bV;
    unsigned short* C       = (z == 0) ? Qb : (z == 1) ? Kb : Vtb;

    const int tid = threadIdx.x, lane = tid & 63, wid = tid >> 6;
    const int l15 = lane & 15, lg = lane >> 4;
    const int wr = wid >> 1, wc = wid & 1;
    const int m0 = blockIdx.x * 128, n0 = blockIdx.y * 128;

    GEMM_CORE(A, W)

    // epilogue: C row = m0+wr*64+mi*16+lg*4+j, col = n0+wc*64+ni*16+l15
#pragma unroll
    for (int ni = 0; ni < 4; ++ni) {
        const int n = n0 + wc * 64 + ni * 16 + l15;
        const float bb = bias[n];
        const int h = n >> 6, d = n & 63;
#pragma unroll
        for (int mi = 0; mi < 4; ++mi) {
            const int mbase = m0 + wr * 64 + mi * 16 + lg * 4;
            if (z != 2) {                       // [B,H,S,Dk]
#pragma unroll
                for (int j = 0; j < 4; ++j) {
                    const int m = mbase + j, b = m >> 11, s = m & 2047;
                    C[(((size_t)(b * HH + h)) * SQ + s) * DK + d] =
                        f2bf(acc[mi][ni][j] + bb);
                }
            } else {                            // V^T [B,H,Dk,Sperm], 8B stores
                u16x4 pk;
#pragma unroll
                for (int j = 0; j < 4; ++j) pk[j] = f2bf(acc[mi][ni][j] + bb);
                const int m = mbase, b = m >> 11, s = m & 2047;   // s % 4 == 0
                const int sp = (s & ~31) | (((s >> 2) & 3) << 3) | (((s >> 4) & 1) << 2);
                *(u16x4*)&C[(((size_t)(b * HH + h)) * DK + d) * SQ + sp] = pk;
            }
        }
    }
}

// Output projection: C = A @ W0^T + b0, A bf16 [8192x1024], C fp32.
__global__ __launch_bounds__(256, 3)
void gemm_out(const unsigned short* __restrict__ Av,
              const unsigned short* __restrict__ Wv,
              const float* __restrict__ bias, float* __restrict__ Cv)
{
    __shared__ char Asb[16384];
    __shared__ char Bsb[16384];

    const int tid = threadIdx.x, lane = tid & 63, wid = tid >> 6;
    const int l15 = lane & 15, lg = lane >> 4;
    const int wr = wid >> 1, wc = wid & 1;
    const int m0 = blockIdx.x * 128, n0 = blockIdx.y * 128;

    GEMM_CORE(Av, Wv)

#pragma unroll
    for (int ni = 0; ni < 4; ++ni) {
        const int n = n0 + wc * 64 + ni * 16 + l15;
        const float bb = bias[n];
#pragma unroll
        for (int mi = 0; mi < 4; ++mi) {
            const int mbase = m0 + wr * 64 + mi * 16 + lg * 4;
#pragma unroll
            for (int j = 0; j < 4; ++j)
                Cv[(size_t)(mbase + j) * DM + n] = acc[mi][ni][j] + bb;
        }
    }
}

// ---------------------------------------------------------------------------
// Flash attention (unchanged), quirk: softmax on UNSCALED scores, /8 after.
// grid = (S/128, B*H); 4 waves; KV tiles of 64, double-buffered LDS.
// Swapped QK^T; softmax in-register; P lane-local via permuted V^T.
// ---------------------------------------------------------------------------
__global__ __launch_bounds__(256, 4)
void flash_attn(const unsigned short* __restrict__ Qb,
                const unsigned short* __restrict__ Kb,
                const unsigned short* __restrict__ Vtb,
                unsigned short* __restrict__ outA)
{
    __shared__ unsigned short Ks[2][64 * 64];    // 2 x 8KB
    __shared__ unsigned short Vs[2][64 * 64];    // 2 x 8KB

    const int tid = threadIdx.x, lane = tid & 63, wid = tid >> 6;
    const int l15 = lane & 15, lg = lane >> 4;
    const int q0 = blockIdx.x * 128;
    const int bh = blockIdx.y;
    const unsigned short* Qp = Qb + (size_t)bh * SQ * DK;
    const unsigned short* Kp = Kb + (size_t)bh * SQ * DK;
    const unsigned short* Vp = Vtb + (size_t)bh * DK * SQ;

    bf16x8 qf[2][2];
#pragma unroll
    for (int mi = 0; mi < 2; ++mi)
#pragma unroll
        for (int ki = 0; ki < 2; ++ki)
            qf[mi][ki] = *(const bf16x8*)&Qp[(size_t)(q0 + wid * 32 + mi * 16 + l15) * DK +
                                             ki * 32 + lg * 8];

    f32x4 O[2][4];          // O^T: row d = di*16+lg*4+j, col q = mi*16+l15
    float mrun[2], lrun[2];
#pragma unroll
    for (int mi = 0; mi < 2; ++mi) { mrun[mi] = -3.0e38f; lrun[mi] = 0.f; }
#pragma unroll
    for (int mi = 0; mi < 2; ++mi)
#pragma unroll
        for (int di = 0; di < 4; ++di) O[mi][di] = (f32x4){0.f, 0.f, 0.f, 0.f};

    const float L2E = 1.44269504089f;

#define STAGE(BUF, KV0) do {                                                   \
        char* Ksb_ = (char*)Ks[BUF]; char* Vsb_ = (char*)Vs[BUF];              \
        _Pragma("unroll")                                                      \
        for (int i_ = 0; i_ < 2; ++i_) {                                       \
            const int p_ = (wid * 2 + i_) * 1024 + lane * 16;                  \
            gll16((const char*)Kp + (size_t)(KV0) * 128 + SWZ128(p_),          \
                  Ksb_ + (wid * 2 + i_) * 1024);                               \
            const int d_ = p_ >> 7;                                            \
            const int cb_ = (p_ ^ ((d_ & 7) << 4)) & 127;                      \
            gll16((const char*)Vp + (size_t)d_ * 4096 + (KV0) * 2 + cb_,       \
                  Vsb_ + (wid * 2 + i_) * 1024);                               \
        } } while (0)

    STAGE(0, 0);
    asm volatile("s_waitcnt vmcnt(0)" ::: "memory");
    __syncthreads();

    for (int kt = 0; kt < 32; ++kt) {
        const int cur = kt & 1;
        const char* Ksb = (const char*)Ks[cur];
        const char* Vsb = (const char*)Vs[cur];
        if (kt < 31) STAGE(cur ^ 1, (kt + 1) * 64);    // prefetch next tile

        f32x4 Sf[2][4];
#pragma unroll
        for (int mi = 0; mi < 2; ++mi)
#pragma unroll
            for (int ni = 0; ni < 4; ++ni) Sf[mi][ni] = (f32x4){0.f, 0.f, 0.f, 0.f};
        __builtin_amdgcn_s_setprio(1);
#pragma unroll
        for (int ki = 0; ki < 2; ++ki) {
#pragma unroll
            for (int ni = 0; ni < 4; ++ni) {
                const int o = (ni * 16 + l15) * 128 + ki * 64 + lg * 16;
                const bf16x8 kf = *(const bf16x8*)(Ksb + SWZ128(o));
                Sf[0][ni] = __builtin_amdgcn_mfma_f32_16x16x32_bf16(kf, qf[0][ki], Sf[0][ni], 0, 0, 0);
                Sf[1][ni] = __builtin_amdgcn_mfma_f32_16x16x32_bf16(kf, qf[1][ki], Sf[1][ni], 0, 0, 0);
            }
        }
        __builtin_amdgcn_s_setprio(0);

#pragma unroll
        for (int mi = 0; mi < 2; ++mi) {
            float tm = Sf[mi][0][0];
#pragma unroll
            for (int ni = 0; ni < 4; ++ni)
#pragma unroll
                for (int j = 0; j < 4; ++j) tm = fmaxf(tm, Sf[mi][ni][j]);
            tm = fmaxf(tm, __shfl_xor(tm, 16));
            tm = fmaxf(tm, __shfl_xor(tm, 32));
            const float mo = mrun[mi];
            if (__all(tm <= mo + 8.0f)) {       // defer: no rescale, keep mo
                float rs = 0.f;
#pragma unroll
                for (int ni = 0; ni < 4; ++ni)
#pragma unroll
                    for (int j = 0; j < 4; ++j) {
                        const float p = __builtin_amdgcn_exp2f((Sf[mi][ni][j] - mo) * L2E);
                        Sf[mi][ni][j] = p;
                        rs += p;
                    }
                rs += __shfl_xor(rs, 16);
                rs += __shfl_xor(rs, 32);
                lrun[mi] += rs;
            } else {
                const float mn = fmaxf(mo, tm);
                const float corr = __builtin_amdgcn_exp2f((mo - mn) * L2E);
                float rs = 0.f;
#pragma unroll
                for (int ni = 0; ni < 4; ++ni)
#pragma unroll
                    for (int j = 0; j < 4; ++j) {
                        const float p = __builtin_amdgcn_exp2f((Sf[mi][ni][j] - mn) * L2E);
                        Sf[mi][ni][j] = p;
                        rs += p;
                    }
                rs += __shfl_xor(rs, 16);
                rs += __shfl_xor(rs, 32);
                lrun[mi] = lrun[mi] * corr + rs;
                mrun[mi] = mn;
#pragma unroll
                for (int di = 0; di < 4; ++di)
#pragma unroll
                    for (int j = 0; j < 4; ++j) O[mi][di][j] *= corr;
            }
        }

#pragma unroll
        for (int kk = 0; kk < 2; ++kk) {
            bf16x8 pf[2];
#pragma unroll
            for (int mi = 0; mi < 2; ++mi) {
                u32x4 pd;
                pd[0] = cvtpk(Sf[mi][2 * kk][0],     Sf[mi][2 * kk][1]);
                pd[1] = cvtpk(Sf[mi][2 * kk][2],     Sf[mi][2 * kk][3]);
                pd[2] = cvtpk(Sf[mi][2 * kk + 1][0], Sf[mi][2 * kk + 1][1]);
                pd[3] = cvtpk(Sf[mi][2 * kk + 1][2], Sf[mi][2 * kk + 1][3]);
                pf[mi] = __builtin_bit_cast(bf16x8, pd);
            }
            __builtin_amdgcn_s_setprio(1);
#pragma unroll
            for (int di = 0; di < 4; ++di) {
                const int o = (di * 16 + l15) * 128 + kk * 64 + lg * 16;
                const bf16x8 vf = *(const bf16x8*)(Vsb + SWZ128(o));
                O[0][di] = __builtin_amdgcn_mfma_f32_16x16x32_bf16(vf, pf[0], O[0][di], 0, 0, 0);
                O[1][di] = __builtin_amdgcn_mfma_f32_16x16x32_bf16(vf, pf[1], O[1][di], 0, 0, 0);
            }
            __builtin_amdgcn_s_setprio(0);
        }

        asm volatile("s_waitcnt vmcnt(0)" ::: "memory");  // prefetch landed
        __syncthreads();
    }

    const int b = bh >> 4, h = bh & 15;
#pragma unroll
    for (int mi = 0; mi < 2; ++mi) {
        const float inv = 1.f / (8.f * lrun[mi]);
        const int q = q0 + wid * 32 + mi * 16 + l15;
#pragma unroll
        for (int di = 0; di < 4; ++di) {
            u16x4 pk;
#pragma unroll
            for (int j = 0; j < 4; ++j) pk[j] = f2bf(O[mi][di][j] * inv);
            *(u16x4*)&outA[((size_t)(b * SQ + q)) * DM + h * DK + di * 16 + lg * 4] = pk;
        }
    }
#undef STAGE
}

// ---------------------------------------------------------------------------
// Scratch map (72MB ws + d_out reuse):
//   ws +0      : Qb   (16MB bf16)
//   ws +NEL    : Kb   (16MB)
//   ws +2*NEL  : Vtb  (16MB)
//   ws +3*NEL  : vb (conv output, dead after gemm_qkv) -> Ab (flash output)
//   ws +4*NEL  : wq(2MB), wk(2MB), wv(2MB), w0(2MB)
//   d_out      : qb (16MB) + kb (16MB) until gemm_out overwrites it (fp32 C)
// ---------------------------------------------------------------------------
extern "C" void kernel_launch(void* const* d_in, const int* in_sizes, int n_in,
                              void* d_out, int out_size, void* d_ws, size_t ws_size,
                              hipStream_t stream)
{
    (void)in_sizes; (void)n_in; (void)out_size; (void)ws_size;
    const float* q  = (const float*)d_in[0];
    const float* k  = (const float*)d_in[1];
    const float* v  = (const float*)d_in[2];
    const float* WQ = (const float*)d_in[3];
    const float* bQ = (const float*)d_in[4];
    const float* WK = (const float*)d_in[5];
    const float* bK = (const float*)d_in[6];
    const float* WV = (const float*)d_in[7];
    const float* bV = (const float*)d_in[8];
    const float* W0 = (const float*)d_in[9];
    const float* b0 = (const float*)d_in[10];

    unsigned short* ws = (unsigned short*)d_ws;
    const size_t NEL = (size_t)MM * DM;          // 8,388,608 elems
    const size_t NW  = (size_t)DM * DM;          // 1,048,576 elems
    unsigned short* Qb  = ws;
    unsigned short* Kb  = ws + NEL;
    unsigned short* Vtb = ws + 2 * NEL;
    unsigned short* vb  = ws + 3 * NEL;          // becomes Ab after gemm_qkv
    unsigned short* Ab  = vb;
    unsigned short* wq  = ws + 4 * NEL;
    unsigned short* wk  = wq + NW;
    unsigned short* wv  = wk + NW;
    unsigned short* w0  = wv + NW;
    unsigned short* qb  = (unsigned short*)d_out;          // d_out as scratch
    unsigned short* kb  = (unsigned short*)d_out + NEL;    // (dead until gemm_out)

    dim3 blk(256);
    hipLaunchKernelGGL(conv_bf16, dim3(2048), blk, 0, stream,
                       q, k, v, WQ, WK, WV, W0, qb, kb, vb, wq, wk, wv, w0);
    hipLaunchKernelGGL(gemm_qkv, dim3(MM / 128, DM / 128, 3), blk, 0, stream,
                       qb, kb, vb, wq, wk, wv, bQ, bK, bV, Qb, Kb, Vtb);
    hipLaunchKernelGGL(flash_attn, dim3(SQ / 128, BQ * HH), blk, 0, stream,
                       Qb, Kb, Vtb, Ab);
    hipLaunchKernelGGL(gemm_out, dim3(MM / 128, DM / 128), blk, 0, stream,
                       Ab, w0, b0, (float*)d_out);
}